// Round 1
// baseline (2075.417 us; speedup 1.0000x reference)
//
#include <hip/hip_runtime.h>
#include <hip/hip_cooperative_groups.h>
#include <math.h>

namespace cg = cooperative_groups;

// ---------------------------------------------------------------------------
// HFPS R12: single cooperative mega-kernel.
// R11 post-mortem: all 45 kernels <51us; ~800us of the 1119 is 44 dependent
// dispatch boundaries (~18us each). Fusion plan:
//   1 dispatch, 256 blocks x 256 thr, 42 grid.sync()s.
//   P0:    block 0 prep (nidx, tbuf, zero accumulators)
//   P1-P8: conv layers on blocks 0..191 (2 units/block);
//          buildAvv tiles on blocks 192..254 (66 tiles/phase, 528 total);
//          block 255 factors diag tile 0 during P2 (its A-tile built in P1).
//   P9:    buildAs strip (all blocks)
//   k=0..15: panelR phase; sync; trail+embedded-next-diag-factor; sync.
// All math identical to R11 kernels (same op order) -> absmax unchanged.
//
// Workspace layout (unchanged):
//   0: lacc  8: nneg  1024: logJ  1088: nidx[1024]
//   8192: hist0  41216: hist1
//   74240: tbuf/ybuf/hbuf0/hbuf1 (4 x 64*2304 fp32)
//   2433536: A (1048*1048 fp64)
// ---------------------------------------------------------------------------

#define NPIX 2304
#define MSZ  4608
#define NOCC 1024
#define NHID 24
#define PF_N 1048

__device__ __forceinline__ float gelu_f(float v){
  float v3 = v*v*v;
  return 0.5f*v*(1.0f + tanhf(0.7978845608028654f*(v + 0.044715f*v3)));
}

// ---- one conv unit: channel c, rowgroup rg; 128 threads (ltid 0..127) ----
__device__ __forceinline__ void conv_unit(int u, int tid,
    const float* __restrict__ in, const float* __restrict__ wgt,
    const float* __restrict__ bias, const float* __restrict__ res,
    float* __restrict__ outp, float* __restrict__ pre_out,
    double* __restrict__ logJ_acc,
    int cin, int resmode, int dogelu, float scale, float pre_scale){
  const int c  = u / 6;
  const int rg = u % 6;
  const int y  = rg*8 + (tid >> 4);
  const int xg = (tid & 15)*3;
  const int ym = ((y+47)%48)*48, y0 = y*48, yp = ((y+1)%48)*48;
  int c5[5];
  #pragma unroll
  for (int t = 0; t < 5; t++){
    int xx = xg - 1 + t;
    c5[t] = (xx < 0) ? 47 : ((xx >= 48) ? xx - 48 : xx);
  }
  float s0 = 0.f, s1 = 0.f, s2 = 0.f;
  const float* wp = wgt + c*cin*9;
  for (int ci = 0; ci < cin; ci++){
    const float* b_ = in + ci*NPIX;
    #pragma unroll
    for (int rr = 0; rr < 3; rr++){
      const int rb = (rr == 0) ? ym : ((rr == 1) ? y0 : yp);
      float v0 = b_[rb+c5[0]], v1 = b_[rb+c5[1]], v2 = b_[rb+c5[2]];
      float v3 = b_[rb+c5[3]], v4 = b_[rb+c5[4]];
      float w0 = wp[3*rr], w1 = wp[3*rr+1], w2 = wp[3*rr+2];
      s0 += v0*w0 + v1*w1 + v2*w2;
      s1 += v1*w0 + v2*w1 + v3*w2;
      s2 += v2*w0 + v3*w1 + v4*w2;
    }
    wp += 9;
  }
  const float bv = bias ? bias[c] : 0.f;
  const int base = c*NPIX + y0 + xg;
  float sv[3] = {s0, s1, s2};
  double ls = 0.0;
  #pragma unroll
  for (int t = 0; t < 3; t++){
    float s = sv[t] + bv;
    if (dogelu) s = gelu_f(s);
    if (resmode == 1) s += res[c*NPIX + y0 + xg + t];
    else if (resmode == 2) s += res[(c>>5)*NPIX + y0 + xg + t];
    s *= scale;
    outp[base+t] = s;
    if (pre_out) pre_out[base+t] = gelu_f(s * pre_scale);
    ls += (double)s;
  }
  if (logJ_acc && c >= 48){
    for (int o = 32; o > 0; o >>= 1) ls += __shfl_down(ls, o, 64);
    if ((tid & 63) == 0) atomicAdd(logJ_acc, ls);
  }
}

// ---- one 32x32 buildAvv tile (whole 256-thread block) ----
__device__ void build_avv_tile(int item, const float* __restrict__ Fvv,
      const int* __restrict__ nidx, double* __restrict__ A,
      float* G1, float* G2, int* sNi, int* sNj){
  __syncthreads();                       // protect LDS reuse across tiles
  int I = 0;
  while ((I+1)*(I+2)/2 <= item) I++;
  const int J = item - I*(I+1)/2;
  const int i0 = I*32, j0 = J*32;
  const int tid = threadIdx.x;
  if (tid < 32) sNi[tid] = nidx[i0+tid];
  else if (tid < 64) sNj[tid-32] = nidx[j0+tid-32];
  __syncthreads();
  for (int idx = tid; idx < 32*32; idx += 256){
    const int r = idx >> 5, c = idx & 31;
    G1[r*33+c] = Fvv[(size_t)sNi[r]*MSZ + sNj[c]];
    G2[r*33+c] = Fvv[(size_t)sNj[r]*MSZ + sNi[c]];
  }
  __syncthreads();
  for (int idx = tid; idx < 32*32; idx += 256){
    const int r = idx >> 5, c = idx & 31;
    const int i = i0 + r, j = j0 + c;
    if (i > j)
      A[(size_t)i*PF_N + j] = 0.5*((double)G1[r*33+c] - (double)G2[c*33+r]);
  }
}

// ---- 2x2-pivot factorization of a diag tile in LDS (unchanged from R11) ----
__device__ __forceinline__ void factor_lds(double* D, double* sTf, int w,
      double* __restrict__ histN, double& lv_out, int& sg_out){
  const int tid = threadIdx.x;
  const int r = tid & 63, qu = tid >> 6;
  const int np = w >> 1;
  for (int j = 0; j < np; j++){
    const int r0 = 2*j, r1 = r0 + 1;
    const double t = -D[r1*65 + r0];
    const double invt = 1.0 / t;
    if (tid == 0) sTf[j] = t;
    const bool rowok = (r < w) && (r >= r0 + 2);
    if (rowok){
      const double ar = D[r*65 + r0], br = D[r*65 + r1];
      if (qu == 0){
        histN[32 + j*64 + r]        = ar * invt;
        histN[32 + 2048 + j*64 + r] = br * invt;
      }
      const int lo = r0 + 2, hi = r;
      const int per = (hi - lo + 3) >> 2;
      const int cb = lo + qu*per;
      int ce = cb + per; if (ce > hi) ce = hi;
      for (int c = cb; c < ce; c++){
        const double ac = D[c*65 + r0], bc = D[c*65 + r1];
        D[r*65 + c] += (br*ac - ar*bc) * invt;
      }
    }
    __syncthreads();
  }
  if (tid < np) histN[tid] = 1.0 / sTf[tid];
  lv_out = 0.0; sg_out = 0;
  if (tid < 64){
    double lv = 0.0; int sg = 0;
    if (tid < np){ double t = sTf[tid]; lv = log(fabs(t)); sg = (t < 0.0) ? 1 : 0; }
    for (int o = 32; o > 0; o >>= 1){
      lv += __shfl_down(lv, o, 64);
      sg += __shfl_down(sg, o, 64);
    }
    if (tid == 0){ lv_out = lv; sg_out = sg; }
  }
}

// ---------------------------------------------------------------------------
__global__ __launch_bounds__(256) void k_mega(
    const float* __restrict__ x, const float* __restrict__ Fvv,
    const float* __restrict__ Fhh,
    const float* __restrict__ w10, const float* __restrict__ b10,
    const float* __restrict__ w20, const float* __restrict__ b20,
    const float* __restrict__ w11, const float* __restrict__ b11,
    const float* __restrict__ w21, const float* __restrict__ b21,
    const float* __restrict__ w12, const float* __restrict__ b12,
    const float* __restrict__ w22, const float* __restrict__ b22,
    const float* __restrict__ w13, const float* __restrict__ b13,
    const float* __restrict__ w23,
    float* __restrict__ outp,
    double* __restrict__ lacc, int* __restrict__ nneg,
    double* __restrict__ logJa, int* __restrict__ nidx,
    double* __restrict__ hist0, double* __restrict__ hist1,
    float* __restrict__ tbuf, float* __restrict__ ybuf,
    float* __restrict__ hbuf0, float* __restrict__ hbuf1,
    double* __restrict__ A){
  cg::grid_group grid = cg::this_grid();
  const int bid = blockIdx.x, tid = threadIdx.x;
  __shared__ double shU[4224];     // 33.8 KB union: prep / G1G2 / D / staging
  __shared__ double sInvL[32];
  __shared__ double sTf[32];

  // ---- P0: prep (block 0): nidx, tbuf = x/sqrt(2), zero accumulators ----
  if (bid == 0){
    int* cnt = (int*)shU; int* off = cnt + 256;
    if (tid == 0){ *lacc = 0.0; *nneg = 0; *logJa = 0.0; }
    int c = 0;
    for (int k2 = 0; k2 < 18; k2++){
      int idx = tid*18 + k2;
      float v = x[idx];
      c += (v == 1.0f) ? 1 : 0;
      tbuf[idx] = v * 0.70710678118654752f;
    }
    cnt[tid] = c;
    __syncthreads();
    if (tid == 0){ int s = 0; for (int q=0;q<256;q++){ off[q]=s; s+=cnt[q]; } }
    __syncthreads();
    int o = off[tid];
    for (int k2 = 0; k2 < 18; k2++){
      int idx = tid*18+k2;
      if (x[idx] == 1.0f) nidx[o++] = idx;
    }
  }
  grid.sync();

  // ---- P1..P8: conv layers (bids 0..191) || buildAvv (192..254)
  //      || panelD0 on bid 255 during P2 ----
  const float* cin_p[8] = {tbuf,ybuf,tbuf,ybuf,tbuf,ybuf,tbuf,ybuf};
  const float* w_p[8]   = {w10,w20,w11,w21,w12,w22,w13,w23};
  const float* b_p[8]   = {b10,b20,b11,b21,b12,b22,b13,nullptr};
  const float* r_p[8]   = {nullptr,x,nullptr,hbuf0,nullptr,hbuf1,nullptr,hbuf0};
  float* o_p[8]         = {ybuf,hbuf0,ybuf,hbuf1,ybuf,hbuf0,ybuf,hbuf1};
  float* pre_p[8]       = {nullptr,tbuf,nullptr,tbuf,nullptr,tbuf,nullptr,nullptr};
  const int   cinn[8]   = {2,64,64,64,64,64,64,64};
  const int   rm[8]     = {0,2,0,1,0,1,0,1};
  const int   dg[8]     = {1,0,1,0,1,0,1,0};
  const float sc[8]     = {1.f,1.f,1.f,1.f,1.f,1.f,1.f,0.44721359549995794f};
  const float ps[8]     = {0.f,0.70710678118654752f,0.f,0.57735026918962576f,
                           0.f,0.5f,0.f,0.f};
  #pragma unroll
  for (int p = 1; p <= 8; p++){
    if (bid < 192){
      conv_unit(bid*2 + (tid>>7), tid & 127,
                cin_p[p-1], w_p[p-1], b_p[p-1], r_p[p-1], o_p[p-1], pre_p[p-1],
                (p == 8) ? logJa : nullptr,
                cinn[p-1], rm[p-1], dg[p-1], sc[p-1], ps[p-1]);
    } else if (bid < 255){
      float* G1 = (float*)shU;
      float* G2 = G1 + 32*33;
      int* sNi = (int*)(G2 + 32*33);
      int* sNj = sNi + 32;
      for (int t = (p-1)*66 + (bid-192); t < p*66; t += 63)
        build_avv_tile(t, Fvv, nidx, A, G1, G2, sNi, sNj);
    } else if (p == 2){
      // diag tile 0 factor (its A-tile was built in P1), hidden under conv L2
      for (int idx = tid; idx < 64*64; idx += 256){
        int r = idx >> 6, c = idx & 63;
        if (r > c) shU[r*65+c] = A[(size_t)r*PF_N + c];
      }
      __syncthreads();
      double lv; int sg;
      factor_lds(shU, sTf, 64, hist0, lv, sg);
      if (tid == 0){ atomicAdd(lacc, lv); atomicAdd(nneg, sg); }
    }
    grid.sync();
  }

  // ---- P9: buildAs strip (rows 1024..1047) ----
  {
    int g0 = bid*256 + tid;
    if (g0 < 24*PF_N){
      const int i = NOCC + g0 / PF_N, j = g0 % PF_N;
      if (j < i){
        const int r = i - NOCC;
        double v;
        if (j < NOCC){
          int nj = nidx[j];
          int ss = (nj >= NPIX) ? 1 : 0;
          v = -(double)hbuf1[(2*r+ss)*NPIX + (nj - ss*NPIX)];
        } else {
          int r2 = j - NOCC;
          v = 0.5*((double)Fhh[r*NHID + r2] - (double)Fhh[r2*NHID + r]);
        }
        A[(size_t)i*PF_N + j] = v;
      }
    }
  }
  grid.sync();

  // ---- Pfaffian loop: 16 x (panelR ; sync ; trail+factor ; sync) ----
  for (int k = 0; k < 16; k++){
    const double* hR = (k & 1) ? hist1 : hist0;
    double* hW = (k & 1) ? hist0 : hist1;
    const int N = PF_N, c0 = 64*k, tc0 = c0 + 64;

    // panelR: one wave per trailing row (256 blocks x 4 waves covers m<=984)
    {
      const int wv = tid >> 6, lc = tid & 63;
      const int i = tc0 + bid*4 + wv;
      if (i < N){
        double v = A[(size_t)i*N + c0 + lc];
        const double* hA = hR + 32;
        const double* hB = hR + 32 + 2048;
        #pragma unroll 8
        for (int j = 0; j < 32; j++){
          double a = __shfl(v, 2*j,   64);
          double b = __shfl(v, 2*j+1, 64);
          if (lc >= 2*j+2) v += b*hA[j*64+lc] - a*hB[j*64+lc];
        }
        A[(size_t)i*N + c0 + lc] = v;
      }
    }
    grid.sync();

    // trail: rank-64 Schur on lower 64x64 tiles + embedded next-diag factor
    {
      const int m = N - tc0;
      const int nt = (m + 63) >> 6;
      const int items = nt*(nt+1)/2;
      double* sPiA = shU;
      double* sPiB = shU + 1056;
      double* sPjA = shU + 2112;
      double* sPjB = shU + 3168;
      const int ty = tid >> 4, tx = tid & 15;
      int i0 = tc0, j0 = tc0, iend = tc0, jend = tc0;
      double acc[4][4];
      if (bid < items){
        {
          int I = 0, item = bid;
          while ((I+1)*(I+2)/2 <= item) I++;
          const int J = item - I*(I+1)/2;
          i0 = tc0 + I*64; j0 = tc0 + J*64;
        }
        iend = (i0 + 64 < N) ? (i0 + 64) : N;
        jend = (j0 + 64 < N) ? (j0 + 64) : N;
        if (tid < 32) sInvL[tid] = hR[tid];
        #pragma unroll
        for (int rr = 0; rr < 4; rr++)
          #pragma unroll
          for (int cc = 0; cc < 4; cc++){
            const int i = i0 + ty + 16*rr, j = j0 + tx + 16*cc;
            acc[rr][cc] = (i < iend && j < jend && i > j) ? A[(size_t)i*N + j] : 0.0;
          }
        __syncthreads();
        #pragma unroll
        for (int lh = 0; lh < 2; lh++){
          #pragma unroll
          for (int u2 = 0; u2 < 4; u2++){
            const int idx = tid + u2*256;
            const int r = idx >> 4, ll = idx & 15;
            const int l = lh*16 + ll;
            const double it = sInvL[l];
            const int gi = i0 + r;
            double a = 0.0, b = 0.0;
            if (gi < iend){
              a = A[(size_t)gi*N + c0 + 2*l];
              b = A[(size_t)gi*N + c0 + 2*l + 1];
            }
            sPiA[ll*66+r] = a; sPiB[ll*66+r] = b;
            const int gj = j0 + r;
            double a2 = 0.0, b2 = 0.0;
            if (gj < jend){
              a2 = A[(size_t)gj*N + c0 + 2*l];
              b2 = A[(size_t)gj*N + c0 + 2*l + 1];
            }
            sPjA[ll*66+r] = a2*it; sPjB[ll*66+r] = b2*it;
          }
          __syncthreads();
          #pragma unroll 4
          for (int ll = 0; ll < 16; ll++){
            double ar[4], br[4], ac2[4], bc2[4];
            #pragma unroll
            for (int rr = 0; rr < 4; rr++){
              ar[rr] = sPiA[ll*66 + ty + 16*rr];
              br[rr] = sPiB[ll*66 + ty + 16*rr];
            }
            #pragma unroll
            for (int cc = 0; cc < 4; cc++){
              ac2[cc] = sPjA[ll*66 + tx + 16*cc];
              bc2[cc] = sPjB[ll*66 + tx + 16*cc];
            }
            #pragma unroll
            for (int rr = 0; rr < 4; rr++)
              #pragma unroll
              for (int cc = 0; cc < 4; cc++)
                acc[rr][cc] += br[rr]*ac2[cc] - ar[rr]*bc2[cc];
          }
          __syncthreads();
        }
        #pragma unroll
        for (int rr = 0; rr < 4; rr++)
          #pragma unroll
          for (int cc = 0; cc < 4; cc++){
            const int i = i0 + ty + 16*rr, j = j0 + tx + 16*cc;
            if (i < iend && j < jend && i > j) A[(size_t)i*N + j] = acc[rr][cc];
          }
      }
      if (bid == 0){
        __syncthreads();
        const int wn = iend - i0;           // 64 or tail 24
        #pragma unroll
        for (int rr = 0; rr < 4; rr++)
          #pragma unroll
          for (int cc = 0; cc < 4; cc++){
            const int i = i0 + ty + 16*rr, j = j0 + tx + 16*cc;
            if (i < iend && j < jend && i > j)
              shU[(i - i0)*65 + (j - j0)] = acc[rr][cc];
          }
        __syncthreads();
        double lv; int sg;
        factor_lds(shU, sTf, wn, hW, lv, sg);
        if (tid == 0){
          double lold = atomicAdd(lacc, lv);
          int sold = atomicAdd(nneg, sg);
          if (k == 15){
            int stot = sold + sg;
            outp[0] = (stot & 1) ? -1.0f : 1.0f;
            outp[1] = (float)(lold + lv + logJa[0]);
          }
        }
      }
      grid.sync();
    }
  }
}

// ---------------------------------------------------------------------------
extern "C" void kernel_launch(void* const* d_in, const int* in_sizes, int n_in,
                              void* d_out, int out_size, void* d_ws, size_t ws_size,
                              hipStream_t stream){
  (void)in_sizes; (void)n_in; (void)out_size; (void)ws_size;
  const float* x   = (const float*)d_in[0];
  const float* Fvv = (const float*)d_in[1];
  const float* Fhh = (const float*)d_in[2];
  const float* w10 = (const float*)d_in[3];
  const float* b10 = (const float*)d_in[4];
  const float* w20 = (const float*)d_in[5];
  const float* b20 = (const float*)d_in[6];
  const float* w11 = (const float*)d_in[7];
  const float* b11 = (const float*)d_in[8];
  const float* w21 = (const float*)d_in[9];
  const float* b21 = (const float*)d_in[10];
  const float* w12 = (const float*)d_in[11];
  const float* b12 = (const float*)d_in[12];
  const float* w22 = (const float*)d_in[13];
  const float* b22 = (const float*)d_in[14];
  const float* w13 = (const float*)d_in[15];
  const float* b13 = (const float*)d_in[16];
  const float* w23 = (const float*)d_in[17];
  float* outp = (float*)d_out;

  char* ws = (char*)d_ws;
  double* lacc  = (double*)(ws + 0);
  int*    nneg  = (int*)(ws + 8);
  double* logJa = (double*)(ws + 1024);
  int*    nidx  = (int*)(ws + 1088);
  double* hist0 = (double*)(ws + 8192);
  double* hist1 = (double*)(ws + 41216);
  const size_t CB = 589824;  // 64*2304*4
  float* tbuf  = (float*)(ws + 74240);
  float* ybuf  = (float*)(ws + 74240 + CB);
  float* hbuf0 = (float*)(ws + 74240 + 2*CB);
  float* hbuf1 = (float*)(ws + 74240 + 3*CB);
  double* A    = (double*)(ws + 74240 + 4*CB);

  void* args[] = { &x,&Fvv,&Fhh,&w10,&b10,&w20,&b20,&w11,&b11,&w21,&b21,
                   &w12,&b12,&w22,&b22,&w13,&b13,&w23,&outp,
                   &lacc,&nneg,&logJa,&nidx,&hist0,&hist1,
                   &tbuf,&ybuf,&hbuf0,&hbuf1,&A };
  hipLaunchCooperativeKernel((void*)k_mega, dim3(256), dim3(256), args, 0, stream);
}

// Round 2
// 1499.193 us; speedup vs baseline: 1.3844x; 1.3844x over previous
//
#include <hip/hip_runtime.h>
#include <math.h>

// ---------------------------------------------------------------------------
// HFPS R13: cooperative mega-kernel with FAST custom grid barrier.
// R12 post-mortem: fusion correct, but cg::grid_group::sync() costs ~47us
// each (s_sleep backoff in __ockl_grid_sync) -> 42 syncs = ~1900us of the
// 2075. VALUBusy 2.6% x 1970us = ~51us of real work. Fix: keep cooperative
// launch (co-residency guarantee) but replace grid.sync with a monotonic
// counter barrier: RELEASE fetch_add + RELAXED agent-scope poll (coherent,
// no per-poll cache inv) + s_sleep(1) + one ACQUIRE agent fence on exit.
//
// Everything else identical to R12 (which was byte-identical math to R11):
//   P0:    block 0 prep (nidx, tbuf, zero accumulators)
//   P1-P8: conv layers on blocks 0..191 (2 units/block);
//          buildAvv tiles on blocks 192..254; block 255 factors diag tile 0
//          during P2.
//   P9:    buildAs strip
//   k=0..15: panelR ; bar ; trail+embedded-next-diag-factor ; bar.
//
// Workspace layout:
//   0: lacc  8: nneg  1024: logJ  1088: nidx[1024]  6144: barrier cnt (8B)
//   8192: hist0  41216: hist1
//   74240: tbuf/ybuf/hbuf0/hbuf1 (4 x 64*2304 fp32)
//   2433536: A (1048*1048 fp64)
// ---------------------------------------------------------------------------

#define NPIX 2304
#define MSZ  4608
#define NOCC 1024
#define NHID 24
#define PF_N 1048
#define GRID 256

__device__ __forceinline__ void gbar(unsigned* cnt, unsigned target){
  __syncthreads();
  if (threadIdx.x == 0){
    __hip_atomic_fetch_add(cnt, 1u, __ATOMIC_RELEASE, __HIP_MEMORY_SCOPE_AGENT);
    while (__hip_atomic_load(cnt, __ATOMIC_RELAXED, __HIP_MEMORY_SCOPE_AGENT)
           < target)
      __builtin_amdgcn_s_sleep(1);
    __builtin_amdgcn_fence(__ATOMIC_ACQUIRE, "agent");
  }
  __syncthreads();
}

__device__ __forceinline__ float gelu_f(float v){
  float v3 = v*v*v;
  return 0.5f*v*(1.0f + tanhf(0.7978845608028654f*(v + 0.044715f*v3)));
}

// ---- one conv unit: channel c, rowgroup rg; 128 threads (ltid 0..127) ----
__device__ __forceinline__ void conv_unit(int u, int tid,
    const float* __restrict__ in, const float* __restrict__ wgt,
    const float* __restrict__ bias, const float* __restrict__ res,
    float* __restrict__ outp, float* __restrict__ pre_out,
    double* __restrict__ logJ_acc,
    int cin, int resmode, int dogelu, float scale, float pre_scale){
  const int c  = u / 6;
  const int rg = u % 6;
  const int y  = rg*8 + (tid >> 4);
  const int xg = (tid & 15)*3;
  const int ym = ((y+47)%48)*48, y0 = y*48, yp = ((y+1)%48)*48;
  int c5[5];
  #pragma unroll
  for (int t = 0; t < 5; t++){
    int xx = xg - 1 + t;
    c5[t] = (xx < 0) ? 47 : ((xx >= 48) ? xx - 48 : xx);
  }
  float s0 = 0.f, s1 = 0.f, s2 = 0.f;
  const float* wp = wgt + c*cin*9;
  for (int ci = 0; ci < cin; ci++){
    const float* b_ = in + ci*NPIX;
    #pragma unroll
    for (int rr = 0; rr < 3; rr++){
      const int rb = (rr == 0) ? ym : ((rr == 1) ? y0 : yp);
      float v0 = b_[rb+c5[0]], v1 = b_[rb+c5[1]], v2 = b_[rb+c5[2]];
      float v3 = b_[rb+c5[3]], v4 = b_[rb+c5[4]];
      float w0 = wp[3*rr], w1 = wp[3*rr+1], w2 = wp[3*rr+2];
      s0 += v0*w0 + v1*w1 + v2*w2;
      s1 += v1*w0 + v2*w1 + v3*w2;
      s2 += v2*w0 + v3*w1 + v4*w2;
    }
    wp += 9;
  }
  const float bv = bias ? bias[c] : 0.f;
  const int base = c*NPIX + y0 + xg;
  float sv[3] = {s0, s1, s2};
  double ls = 0.0;
  #pragma unroll
  for (int t = 0; t < 3; t++){
    float s = sv[t] + bv;
    if (dogelu) s = gelu_f(s);
    if (resmode == 1) s += res[c*NPIX + y0 + xg + t];
    else if (resmode == 2) s += res[(c>>5)*NPIX + y0 + xg + t];
    s *= scale;
    outp[base+t] = s;
    if (pre_out) pre_out[base+t] = gelu_f(s * pre_scale);
    ls += (double)s;
  }
  if (logJ_acc && c >= 48){
    for (int o = 32; o > 0; o >>= 1) ls += __shfl_down(ls, o, 64);
    if ((tid & 63) == 0) atomicAdd(logJ_acc, ls);
  }
}

// ---- one 32x32 buildAvv tile (whole 256-thread block) ----
__device__ void build_avv_tile(int item, const float* __restrict__ Fvv,
      const int* __restrict__ nidx, double* __restrict__ A,
      float* G1, float* G2, int* sNi, int* sNj){
  __syncthreads();                       // protect LDS reuse across tiles
  int I = 0;
  while ((I+1)*(I+2)/2 <= item) I++;
  const int J = item - I*(I+1)/2;
  const int i0 = I*32, j0 = J*32;
  const int tid = threadIdx.x;
  if (tid < 32) sNi[tid] = nidx[i0+tid];
  else if (tid < 64) sNj[tid-32] = nidx[j0+tid-32];
  __syncthreads();
  for (int idx = tid; idx < 32*32; idx += 256){
    const int r = idx >> 5, c = idx & 31;
    G1[r*33+c] = Fvv[(size_t)sNi[r]*MSZ + sNj[c]];
    G2[r*33+c] = Fvv[(size_t)sNj[r]*MSZ + sNi[c]];
  }
  __syncthreads();
  for (int idx = tid; idx < 32*32; idx += 256){
    const int r = idx >> 5, c = idx & 31;
    const int i = i0 + r, j = j0 + c;
    if (i > j)
      A[(size_t)i*PF_N + j] = 0.5*((double)G1[r*33+c] - (double)G2[c*33+r]);
  }
}

// ---- 2x2-pivot factorization of a diag tile in LDS (unchanged) ----
__device__ __forceinline__ void factor_lds(double* D, double* sTf, int w,
      double* __restrict__ histN, double& lv_out, int& sg_out){
  const int tid = threadIdx.x;
  const int r = tid & 63, qu = tid >> 6;
  const int np = w >> 1;
  for (int j = 0; j < np; j++){
    const int r0 = 2*j, r1 = r0 + 1;
    const double t = -D[r1*65 + r0];
    const double invt = 1.0 / t;
    if (tid == 0) sTf[j] = t;
    const bool rowok = (r < w) && (r >= r0 + 2);
    if (rowok){
      const double ar = D[r*65 + r0], br = D[r*65 + r1];
      if (qu == 0){
        histN[32 + j*64 + r]        = ar * invt;
        histN[32 + 2048 + j*64 + r] = br * invt;
      }
      const int lo = r0 + 2, hi = r;
      const int per = (hi - lo + 3) >> 2;
      const int cb = lo + qu*per;
      int ce = cb + per; if (ce > hi) ce = hi;
      for (int c = cb; c < ce; c++){
        const double ac = D[c*65 + r0], bc = D[c*65 + r1];
        D[r*65 + c] += (br*ac - ar*bc) * invt;
      }
    }
    __syncthreads();
  }
  if (tid < np) histN[tid] = 1.0 / sTf[tid];
  lv_out = 0.0; sg_out = 0;
  if (tid < 64){
    double lv = 0.0; int sg = 0;
    if (tid < np){ double t = sTf[tid]; lv = log(fabs(t)); sg = (t < 0.0) ? 1 : 0; }
    for (int o = 32; o > 0; o >>= 1){
      lv += __shfl_down(lv, o, 64);
      sg += __shfl_down(sg, o, 64);
    }
    if (tid == 0){ lv_out = lv; sg_out = sg; }
  }
}

// ---------------------------------------------------------------------------
__global__ __launch_bounds__(256) void k_mega(
    const float* __restrict__ x, const float* __restrict__ Fvv,
    const float* __restrict__ Fhh,
    const float* __restrict__ w10, const float* __restrict__ b10,
    const float* __restrict__ w20, const float* __restrict__ b20,
    const float* __restrict__ w11, const float* __restrict__ b11,
    const float* __restrict__ w21, const float* __restrict__ b21,
    const float* __restrict__ w12, const float* __restrict__ b12,
    const float* __restrict__ w22, const float* __restrict__ b22,
    const float* __restrict__ w13, const float* __restrict__ b13,
    const float* __restrict__ w23,
    float* __restrict__ outp,
    double* __restrict__ lacc, int* __restrict__ nneg,
    double* __restrict__ logJa, int* __restrict__ nidx,
    double* __restrict__ hist0, double* __restrict__ hist1,
    float* __restrict__ tbuf, float* __restrict__ ybuf,
    float* __restrict__ hbuf0, float* __restrict__ hbuf1,
    double* __restrict__ A, unsigned* __restrict__ bcnt){
  const int bid = blockIdx.x, tid = threadIdx.x;
  unsigned bar = 0;                // monotonic barrier target
  __shared__ double shU[4224];     // 33.8 KB union: prep / G1G2 / D / staging
  __shared__ double sInvL[32];
  __shared__ double sTf[32];

  // ---- P0: prep (block 0): nidx, tbuf = x/sqrt(2), zero accumulators ----
  if (bid == 0){
    int* cnt = (int*)shU; int* off = cnt + 256;
    if (tid == 0){ *lacc = 0.0; *nneg = 0; *logJa = 0.0; }
    int c = 0;
    for (int k2 = 0; k2 < 18; k2++){
      int idx = tid*18 + k2;
      float v = x[idx];
      c += (v == 1.0f) ? 1 : 0;
      tbuf[idx] = v * 0.70710678118654752f;
    }
    cnt[tid] = c;
    __syncthreads();
    if (tid == 0){ int s = 0; for (int q=0;q<256;q++){ off[q]=s; s+=cnt[q]; } }
    __syncthreads();
    int o = off[tid];
    for (int k2 = 0; k2 < 18; k2++){
      int idx = tid*18+k2;
      if (x[idx] == 1.0f) nidx[o++] = idx;
    }
  }
  gbar(bcnt, bar += GRID);

  // ---- P1..P8: conv layers (bids 0..191) || buildAvv (192..254)
  //      || panelD0 on bid 255 during P2 ----
  const float* cin_p[8] = {tbuf,ybuf,tbuf,ybuf,tbuf,ybuf,tbuf,ybuf};
  const float* w_p[8]   = {w10,w20,w11,w21,w12,w22,w13,w23};
  const float* b_p[8]   = {b10,b20,b11,b21,b12,b22,b13,nullptr};
  const float* r_p[8]   = {nullptr,x,nullptr,hbuf0,nullptr,hbuf1,nullptr,hbuf0};
  float* o_p[8]         = {ybuf,hbuf0,ybuf,hbuf1,ybuf,hbuf0,ybuf,hbuf1};
  float* pre_p[8]       = {nullptr,tbuf,nullptr,tbuf,nullptr,tbuf,nullptr,nullptr};
  const int   cinn[8]   = {2,64,64,64,64,64,64,64};
  const int   rm[8]     = {0,2,0,1,0,1,0,1};
  const int   dg[8]     = {1,0,1,0,1,0,1,0};
  const float sc[8]     = {1.f,1.f,1.f,1.f,1.f,1.f,1.f,0.44721359549995794f};
  const float ps[8]     = {0.f,0.70710678118654752f,0.f,0.57735026918962576f,
                           0.f,0.5f,0.f,0.f};
  #pragma unroll
  for (int p = 1; p <= 8; p++){
    if (bid < 192){
      conv_unit(bid*2 + (tid>>7), tid & 127,
                cin_p[p-1], w_p[p-1], b_p[p-1], r_p[p-1], o_p[p-1], pre_p[p-1],
                (p == 8) ? logJa : nullptr,
                cinn[p-1], rm[p-1], dg[p-1], sc[p-1], ps[p-1]);
    } else if (bid < 255){
      float* G1 = (float*)shU;
      float* G2 = G1 + 32*33;
      int* sNi = (int*)(G2 + 32*33);
      int* sNj = sNi + 32;
      for (int t = (p-1)*66 + (bid-192); t < p*66; t += 63)
        build_avv_tile(t, Fvv, nidx, A, G1, G2, sNi, sNj);
    } else if (p == 2){
      // diag tile 0 factor (A-tile built in P1), hidden under conv L2
      for (int idx = tid; idx < 64*64; idx += 256){
        int r = idx >> 6, c = idx & 63;
        if (r > c) shU[r*65+c] = A[(size_t)r*PF_N + c];
      }
      __syncthreads();
      double lv; int sg;
      factor_lds(shU, sTf, 64, hist0, lv, sg);
      if (tid == 0){ atomicAdd(lacc, lv); atomicAdd(nneg, sg); }
    }
    gbar(bcnt, bar += GRID);
  }

  // ---- P9: buildAs strip (rows 1024..1047) ----
  {
    int g0 = bid*256 + tid;
    if (g0 < 24*PF_N){
      const int i = NOCC + g0 / PF_N, j = g0 % PF_N;
      if (j < i){
        const int r = i - NOCC;
        double v;
        if (j < NOCC){
          int nj = nidx[j];
          int ss = (nj >= NPIX) ? 1 : 0;
          v = -(double)hbuf1[(2*r+ss)*NPIX + (nj - ss*NPIX)];
        } else {
          int r2 = j - NOCC;
          v = 0.5*((double)Fhh[r*NHID + r2] - (double)Fhh[r2*NHID + r]);
        }
        A[(size_t)i*PF_N + j] = v;
      }
    }
  }
  gbar(bcnt, bar += GRID);

  // ---- Pfaffian loop: 16 x (panelR ; bar ; trail+factor ; bar) ----
  for (int k = 0; k < 16; k++){
    const double* hR = (k & 1) ? hist1 : hist0;
    double* hW = (k & 1) ? hist0 : hist1;
    const int N = PF_N, c0 = 64*k, tc0 = c0 + 64;

    // panelR: one wave per trailing row
    {
      const int wv = tid >> 6, lc = tid & 63;
      const int i = tc0 + bid*4 + wv;
      if (i < N){
        double v = A[(size_t)i*N + c0 + lc];
        const double* hA = hR + 32;
        const double* hB = hR + 32 + 2048;
        #pragma unroll 8
        for (int j = 0; j < 32; j++){
          double a = __shfl(v, 2*j,   64);
          double b = __shfl(v, 2*j+1, 64);
          if (lc >= 2*j+2) v += b*hA[j*64+lc] - a*hB[j*64+lc];
        }
        A[(size_t)i*N + c0 + lc] = v;
      }
    }
    gbar(bcnt, bar += GRID);

    // trail: rank-64 Schur on lower 64x64 tiles + embedded next-diag factor
    {
      const int m = N - tc0;
      const int nt = (m + 63) >> 6;
      const int items = nt*(nt+1)/2;
      double* sPiA = shU;
      double* sPiB = shU + 1056;
      double* sPjA = shU + 2112;
      double* sPjB = shU + 3168;
      const int ty = tid >> 4, tx = tid & 15;
      int i0 = tc0, j0 = tc0, iend = tc0, jend = tc0;
      double acc[4][4];
      if (bid < items){
        {
          int I = 0, item = bid;
          while ((I+1)*(I+2)/2 <= item) I++;
          const int J = item - I*(I+1)/2;
          i0 = tc0 + I*64; j0 = tc0 + J*64;
        }
        iend = (i0 + 64 < N) ? (i0 + 64) : N;
        jend = (j0 + 64 < N) ? (j0 + 64) : N;
        if (tid < 32) sInvL[tid] = hR[tid];
        #pragma unroll
        for (int rr = 0; rr < 4; rr++)
          #pragma unroll
          for (int cc = 0; cc < 4; cc++){
            const int i = i0 + ty + 16*rr, j = j0 + tx + 16*cc;
            acc[rr][cc] = (i < iend && j < jend && i > j) ? A[(size_t)i*N + j] : 0.0;
          }
        __syncthreads();
        #pragma unroll
        for (int lh = 0; lh < 2; lh++){
          #pragma unroll
          for (int u2 = 0; u2 < 4; u2++){
            const int idx = tid + u2*256;
            const int r = idx >> 4, ll = idx & 15;
            const int l = lh*16 + ll;
            const double it = sInvL[l];
            const int gi = i0 + r;
            double a = 0.0, b = 0.0;
            if (gi < iend){
              a = A[(size_t)gi*N + c0 + 2*l];
              b = A[(size_t)gi*N + c0 + 2*l + 1];
            }
            sPiA[ll*66+r] = a; sPiB[ll*66+r] = b;
            const int gj = j0 + r;
            double a2 = 0.0, b2 = 0.0;
            if (gj < jend){
              a2 = A[(size_t)gj*N + c0 + 2*l];
              b2 = A[(size_t)gj*N + c0 + 2*l + 1];
            }
            sPjA[ll*66+r] = a2*it; sPjB[ll*66+r] = b2*it;
          }
          __syncthreads();
          #pragma unroll 4
          for (int ll = 0; ll < 16; ll++){
            double ar[4], br[4], ac2[4], bc2[4];
            #pragma unroll
            for (int rr = 0; rr < 4; rr++){
              ar[rr] = sPiA[ll*66 + ty + 16*rr];
              br[rr] = sPiB[ll*66 + ty + 16*rr];
            }
            #pragma unroll
            for (int cc = 0; cc < 4; cc++){
              ac2[cc] = sPjA[ll*66 + tx + 16*cc];
              bc2[cc] = sPjB[ll*66 + tx + 16*cc];
            }
            #pragma unroll
            for (int rr = 0; rr < 4; rr++)
              #pragma unroll
              for (int cc = 0; cc < 4; cc++)
                acc[rr][cc] += br[rr]*ac2[cc] - ar[rr]*bc2[cc];
          }
          __syncthreads();
        }
        #pragma unroll
        for (int rr = 0; rr < 4; rr++)
          #pragma unroll
          for (int cc = 0; cc < 4; cc++){
            const int i = i0 + ty + 16*rr, j = j0 + tx + 16*cc;
            if (i < iend && j < jend && i > j) A[(size_t)i*N + j] = acc[rr][cc];
          }
      }
      if (bid == 0){
        __syncthreads();
        const int wn = iend - i0;           // 64 or tail 24
        #pragma unroll
        for (int rr = 0; rr < 4; rr++)
          #pragma unroll
          for (int cc = 0; cc < 4; cc++){
            const int i = i0 + ty + 16*rr, j = j0 + tx + 16*cc;
            if (i < iend && j < jend && i > j)
              shU[(i - i0)*65 + (j - j0)] = acc[rr][cc];
          }
        __syncthreads();
        double lv; int sg;
        factor_lds(shU, sTf, wn, hW, lv, sg);
        if (tid == 0){
          double lold = atomicAdd(lacc, lv);
          int sold = atomicAdd(nneg, sg);
          if (k == 15){
            int stot = sold + sg;
            outp[0] = (stot & 1) ? -1.0f : 1.0f;
            outp[1] = (float)(lold + lv + logJa[0]);
          }
        }
      }
      gbar(bcnt, bar += GRID);
    }
  }
}

// ---------------------------------------------------------------------------
extern "C" void kernel_launch(void* const* d_in, const int* in_sizes, int n_in,
                              void* d_out, int out_size, void* d_ws, size_t ws_size,
                              hipStream_t stream){
  (void)in_sizes; (void)n_in; (void)out_size; (void)ws_size;
  const float* x   = (const float*)d_in[0];
  const float* Fvv = (const float*)d_in[1];
  const float* Fhh = (const float*)d_in[2];
  const float* w10 = (const float*)d_in[3];
  const float* b10 = (const float*)d_in[4];
  const float* w20 = (const float*)d_in[5];
  const float* b20 = (const float*)d_in[6];
  const float* w11 = (const float*)d_in[7];
  const float* b11 = (const float*)d_in[8];
  const float* w21 = (const float*)d_in[9];
  const float* b21 = (const float*)d_in[10];
  const float* w12 = (const float*)d_in[11];
  const float* b12 = (const float*)d_in[12];
  const float* w22 = (const float*)d_in[13];
  const float* b22 = (const float*)d_in[14];
  const float* w13 = (const float*)d_in[15];
  const float* b13 = (const float*)d_in[16];
  const float* w23 = (const float*)d_in[17];
  float* outp = (float*)d_out;

  char* ws = (char*)d_ws;
  double* lacc  = (double*)(ws + 0);
  int*    nneg  = (int*)(ws + 8);
  double* logJa = (double*)(ws + 1024);
  int*    nidx  = (int*)(ws + 1088);
  unsigned* bcnt = (unsigned*)(ws + 6144);
  double* hist0 = (double*)(ws + 8192);
  double* hist1 = (double*)(ws + 41216);
  const size_t CB = 589824;  // 64*2304*4
  float* tbuf  = (float*)(ws + 74240);
  float* ybuf  = (float*)(ws + 74240 + CB);
  float* hbuf0 = (float*)(ws + 74240 + 2*CB);
  float* hbuf1 = (float*)(ws + 74240 + 3*CB);
  double* A    = (double*)(ws + 74240 + 4*CB);

  hipMemsetAsync(ws + 6144, 0, 8, stream);   // barrier counter

  void* args[] = { &x,&Fvv,&Fhh,&w10,&b10,&w20,&b20,&w11,&b11,&w21,&b21,
                   &w12,&b12,&w22,&b22,&w13,&b13,&w23,&outp,
                   &lacc,&nneg,&logJa,&nidx,&hist0,&hist1,
                   &tbuf,&ybuf,&hbuf0,&hbuf1,&A,&bcnt };
  hipLaunchCooperativeKernel((void*)k_mega, dim3(256), dim3(256), args, 0, stream);
}

// Round 3
// 1415.058 us; speedup vs baseline: 1.4667x; 1.0595x over previous
//
#include <hip/hip_runtime.h>
#include <math.h>

// ---------------------------------------------------------------------------
// HFPS R14: cooperative mega-kernel, tree barrier with coherent polls.
// R13 post-mortem: barrier still ~24us each. FETCH unchanged (no refetch
// storm) + VALU work unchanged => stall is STALE-LINE POLLING: relaxed
// AGENT loads can hit the local XCD L2; fetch_adds execute at LLC and never
// update remote L2 copies, so pollers progress only on line EVICTION
// (~20-30us). Fix:
//   - poll with SYSTEM-scope relaxed load (sc0 sc1 -> bypasses L1+L2).
//   - 2-level tree: 8 group counters (bid>>5, own 128B lines, <=32 RMW each)
//     + global epoch counter (8 RMWs); everyone polls global.
//   - release on adds (keeps per-XCD L2 writeback for data), one agent
//     acquire fence on exit.
// Everything else identical to R13 (math identical to R11).
//
// Workspace layout:
//   0: lacc  8: nneg  1024: logJ  1088: nidx[1024]
//   6144: grp_cnt[8] (128B apart)  7168: global epoch cnt
//   8192: hist0  41216: hist1
//   74240: tbuf/ybuf/hbuf0/hbuf1 (4 x 64*2304 fp32)
//   2433536: A (1048*1048 fp64)
// ---------------------------------------------------------------------------

#define NPIX 2304
#define MSZ  4608
#define NOCC 1024
#define NHID 24
#define PF_N 1048
#define GRID 256
#define NGRP 8
#define GRPSZ 32

__device__ __forceinline__ void gbar(unsigned* grp_cnt, unsigned* gcnt,
                                     unsigned epoch){
  __syncthreads();
  if (threadIdx.x == 0){
    unsigned* mycnt = grp_cnt + (blockIdx.x >> 5) * 32;   // 128B-spaced lines
    unsigned old = __hip_atomic_fetch_add(mycnt, 1u, __ATOMIC_RELEASE,
                                          __HIP_MEMORY_SCOPE_AGENT);
    if (old + 1u == epoch * GRPSZ){
      __hip_atomic_fetch_add(gcnt, 1u, __ATOMIC_RELEASE,
                             __HIP_MEMORY_SCOPE_AGENT);
    }
    while (__hip_atomic_load(gcnt, __ATOMIC_RELAXED,
                             __HIP_MEMORY_SCOPE_SYSTEM) < epoch * NGRP)
      __builtin_amdgcn_s_sleep(2);
    __builtin_amdgcn_fence(__ATOMIC_ACQUIRE, "agent");
  }
  __syncthreads();
}

__device__ __forceinline__ float gelu_f(float v){
  float v3 = v*v*v;
  return 0.5f*v*(1.0f + tanhf(0.7978845608028654f*(v + 0.044715f*v3)));
}

// ---- one conv unit: channel c, rowgroup rg; 128 threads (ltid 0..127) ----
__device__ __forceinline__ void conv_unit(int u, int tid,
    const float* __restrict__ in, const float* __restrict__ wgt,
    const float* __restrict__ bias, const float* __restrict__ res,
    float* __restrict__ outp, float* __restrict__ pre_out,
    double* __restrict__ logJ_acc,
    int cin, int resmode, int dogelu, float scale, float pre_scale){
  const int c  = u / 6;
  const int rg = u % 6;
  const int y  = rg*8 + (tid >> 4);
  const int xg = (tid & 15)*3;
  const int ym = ((y+47)%48)*48, y0 = y*48, yp = ((y+1)%48)*48;
  int c5[5];
  #pragma unroll
  for (int t = 0; t < 5; t++){
    int xx = xg - 1 + t;
    c5[t] = (xx < 0) ? 47 : ((xx >= 48) ? xx - 48 : xx);
  }
  float s0 = 0.f, s1 = 0.f, s2 = 0.f;
  const float* wp = wgt + c*cin*9;
  for (int ci = 0; ci < cin; ci++){
    const float* b_ = in + ci*NPIX;
    #pragma unroll
    for (int rr = 0; rr < 3; rr++){
      const int rb = (rr == 0) ? ym : ((rr == 1) ? y0 : yp);
      float v0 = b_[rb+c5[0]], v1 = b_[rb+c5[1]], v2 = b_[rb+c5[2]];
      float v3 = b_[rb+c5[3]], v4 = b_[rb+c5[4]];
      float w0 = wp[3*rr], w1 = wp[3*rr+1], w2 = wp[3*rr+2];
      s0 += v0*w0 + v1*w1 + v2*w2;
      s1 += v1*w0 + v2*w1 + v3*w2;
      s2 += v2*w0 + v3*w1 + v4*w2;
    }
    wp += 9;
  }
  const float bv = bias ? bias[c] : 0.f;
  const int base = c*NPIX + y0 + xg;
  float sv[3] = {s0, s1, s2};
  double ls = 0.0;
  #pragma unroll
  for (int t = 0; t < 3; t++){
    float s = sv[t] + bv;
    if (dogelu) s = gelu_f(s);
    if (resmode == 1) s += res[c*NPIX + y0 + xg + t];
    else if (resmode == 2) s += res[(c>>5)*NPIX + y0 + xg + t];
    s *= scale;
    outp[base+t] = s;
    if (pre_out) pre_out[base+t] = gelu_f(s * pre_scale);
    ls += (double)s;
  }
  if (logJ_acc && c >= 48){
    for (int o = 32; o > 0; o >>= 1) ls += __shfl_down(ls, o, 64);
    if ((tid & 63) == 0) atomicAdd(logJ_acc, ls);
  }
}

// ---- one 32x32 buildAvv tile (whole 256-thread block) ----
__device__ void build_avv_tile(int item, const float* __restrict__ Fvv,
      const int* __restrict__ nidx, double* __restrict__ A,
      float* G1, float* G2, int* sNi, int* sNj){
  __syncthreads();                       // protect LDS reuse across tiles
  int I = 0;
  while ((I+1)*(I+2)/2 <= item) I++;
  const int J = item - I*(I+1)/2;
  const int i0 = I*32, j0 = J*32;
  const int tid = threadIdx.x;
  if (tid < 32) sNi[tid] = nidx[i0+tid];
  else if (tid < 64) sNj[tid-32] = nidx[j0+tid-32];
  __syncthreads();
  for (int idx = tid; idx < 32*32; idx += 256){
    const int r = idx >> 5, c = idx & 31;
    G1[r*33+c] = Fvv[(size_t)sNi[r]*MSZ + sNj[c]];
    G2[r*33+c] = Fvv[(size_t)sNj[r]*MSZ + sNi[c]];
  }
  __syncthreads();
  for (int idx = tid; idx < 32*32; idx += 256){
    const int r = idx >> 5, c = idx & 31;
    const int i = i0 + r, j = j0 + c;
    if (i > j)
      A[(size_t)i*PF_N + j] = 0.5*((double)G1[r*33+c] - (double)G2[c*33+r]);
  }
}

// ---- 2x2-pivot factorization of a diag tile in LDS (unchanged) ----
__device__ __forceinline__ void factor_lds(double* D, double* sTf, int w,
      double* __restrict__ histN, double& lv_out, int& sg_out){
  const int tid = threadIdx.x;
  const int r = tid & 63, qu = tid >> 6;
  const int np = w >> 1;
  for (int j = 0; j < np; j++){
    const int r0 = 2*j, r1 = r0 + 1;
    const double t = -D[r1*65 + r0];
    const double invt = 1.0 / t;
    if (tid == 0) sTf[j] = t;
    const bool rowok = (r < w) && (r >= r0 + 2);
    if (rowok){
      const double ar = D[r*65 + r0], br = D[r*65 + r1];
      if (qu == 0){
        histN[32 + j*64 + r]        = ar * invt;
        histN[32 + 2048 + j*64 + r] = br * invt;
      }
      const int lo = r0 + 2, hi = r;
      const int per = (hi - lo + 3) >> 2;
      const int cb = lo + qu*per;
      int ce = cb + per; if (ce > hi) ce = hi;
      for (int c = cb; c < ce; c++){
        const double ac = D[c*65 + r0], bc = D[c*65 + r1];
        D[r*65 + c] += (br*ac - ar*bc) * invt;
      }
    }
    __syncthreads();
  }
  if (tid < np) histN[tid] = 1.0 / sTf[tid];
  lv_out = 0.0; sg_out = 0;
  if (tid < 64){
    double lv = 0.0; int sg = 0;
    if (tid < np){ double t = sTf[tid]; lv = log(fabs(t)); sg = (t < 0.0) ? 1 : 0; }
    for (int o = 32; o > 0; o >>= 1){
      lv += __shfl_down(lv, o, 64);
      sg += __shfl_down(sg, o, 64);
    }
    if (tid == 0){ lv_out = lv; sg_out = sg; }
  }
}

// ---------------------------------------------------------------------------
__global__ __launch_bounds__(256) void k_mega(
    const float* __restrict__ x, const float* __restrict__ Fvv,
    const float* __restrict__ Fhh,
    const float* __restrict__ w10, const float* __restrict__ b10,
    const float* __restrict__ w20, const float* __restrict__ b20,
    const float* __restrict__ w11, const float* __restrict__ b11,
    const float* __restrict__ w21, const float* __restrict__ b21,
    const float* __restrict__ w12, const float* __restrict__ b12,
    const float* __restrict__ w22, const float* __restrict__ b22,
    const float* __restrict__ w13, const float* __restrict__ b13,
    const float* __restrict__ w23,
    float* __restrict__ outp,
    double* __restrict__ lacc, int* __restrict__ nneg,
    double* __restrict__ logJa, int* __restrict__ nidx,
    double* __restrict__ hist0, double* __restrict__ hist1,
    float* __restrict__ tbuf, float* __restrict__ ybuf,
    float* __restrict__ hbuf0, float* __restrict__ hbuf1,
    double* __restrict__ A, unsigned* __restrict__ grp_cnt,
    unsigned* __restrict__ gcnt){
  const int bid = blockIdx.x, tid = threadIdx.x;
  unsigned ep = 0;                 // barrier epoch
  __shared__ double shU[4224];     // 33.8 KB union: prep / G1G2 / D / staging
  __shared__ double sInvL[32];
  __shared__ double sTf[32];

  // ---- P0: prep (block 0): nidx, tbuf = x/sqrt(2), zero accumulators ----
  if (bid == 0){
    int* cnt = (int*)shU; int* off = cnt + 256;
    if (tid == 0){ *lacc = 0.0; *nneg = 0; *logJa = 0.0; }
    int c = 0;
    for (int k2 = 0; k2 < 18; k2++){
      int idx = tid*18 + k2;
      float v = x[idx];
      c += (v == 1.0f) ? 1 : 0;
      tbuf[idx] = v * 0.70710678118654752f;
    }
    cnt[tid] = c;
    __syncthreads();
    if (tid == 0){ int s = 0; for (int q=0;q<256;q++){ off[q]=s; s+=cnt[q]; } }
    __syncthreads();
    int o = off[tid];
    for (int k2 = 0; k2 < 18; k2++){
      int idx = tid*18+k2;
      if (x[idx] == 1.0f) nidx[o++] = idx;
    }
  }
  gbar(grp_cnt, gcnt, ++ep);

  // ---- P1..P8: conv layers (bids 0..191) || buildAvv (192..254)
  //      || panelD0 on bid 255 during P2 ----
  const float* cin_p[8] = {tbuf,ybuf,tbuf,ybuf,tbuf,ybuf,tbuf,ybuf};
  const float* w_p[8]   = {w10,w20,w11,w21,w12,w22,w13,w23};
  const float* b_p[8]   = {b10,b20,b11,b21,b12,b22,b13,nullptr};
  const float* r_p[8]   = {nullptr,x,nullptr,hbuf0,nullptr,hbuf1,nullptr,hbuf0};
  float* o_p[8]         = {ybuf,hbuf0,ybuf,hbuf1,ybuf,hbuf0,ybuf,hbuf1};
  float* pre_p[8]       = {nullptr,tbuf,nullptr,tbuf,nullptr,tbuf,nullptr,nullptr};
  const int   cinn[8]   = {2,64,64,64,64,64,64,64};
  const int   rm[8]     = {0,2,0,1,0,1,0,1};
  const int   dg[8]     = {1,0,1,0,1,0,1,0};
  const float sc[8]     = {1.f,1.f,1.f,1.f,1.f,1.f,1.f,0.44721359549995794f};
  const float ps[8]     = {0.f,0.70710678118654752f,0.f,0.57735026918962576f,
                           0.f,0.5f,0.f,0.f};
  #pragma unroll
  for (int p = 1; p <= 8; p++){
    if (bid < 192){
      conv_unit(bid*2 + (tid>>7), tid & 127,
                cin_p[p-1], w_p[p-1], b_p[p-1], r_p[p-1], o_p[p-1], pre_p[p-1],
                (p == 8) ? logJa : nullptr,
                cinn[p-1], rm[p-1], dg[p-1], sc[p-1], ps[p-1]);
    } else if (bid < 255){
      float* G1 = (float*)shU;
      float* G2 = G1 + 32*33;
      int* sNi = (int*)(G2 + 32*33);
      int* sNj = sNi + 32;
      for (int t = (p-1)*66 + (bid-192); t < p*66; t += 63)
        build_avv_tile(t, Fvv, nidx, A, G1, G2, sNi, sNj);
    } else if (p == 2){
      // diag tile 0 factor (A-tile built in P1), hidden under conv L2
      for (int idx = tid; idx < 64*64; idx += 256){
        int r = idx >> 6, c = idx & 63;
        if (r > c) shU[r*65+c] = A[(size_t)r*PF_N + c];
      }
      __syncthreads();
      double lv; int sg;
      factor_lds(shU, sTf, 64, hist0, lv, sg);
      if (tid == 0){ atomicAdd(lacc, lv); atomicAdd(nneg, sg); }
    }
    gbar(grp_cnt, gcnt, ++ep);
  }

  // ---- P9: buildAs strip (rows 1024..1047) ----
  {
    int g0 = bid*256 + tid;
    if (g0 < 24*PF_N){
      const int i = NOCC + g0 / PF_N, j = g0 % PF_N;
      if (j < i){
        const int r = i - NOCC;
        double v;
        if (j < NOCC){
          int nj = nidx[j];
          int ss = (nj >= NPIX) ? 1 : 0;
          v = -(double)hbuf1[(2*r+ss)*NPIX + (nj - ss*NPIX)];
        } else {
          int r2 = j - NOCC;
          v = 0.5*((double)Fhh[r*NHID + r2] - (double)Fhh[r2*NHID + r]);
        }
        A[(size_t)i*PF_N + j] = v;
      }
    }
  }
  gbar(grp_cnt, gcnt, ++ep);

  // ---- Pfaffian loop: 16 x (panelR ; bar ; trail+factor ; bar) ----
  for (int k = 0; k < 16; k++){
    const double* hR = (k & 1) ? hist1 : hist0;
    double* hW = (k & 1) ? hist0 : hist1;
    const int N = PF_N, c0 = 64*k, tc0 = c0 + 64;

    // panelR: one wave per trailing row
    {
      const int wv = tid >> 6, lc = tid & 63;
      const int i = tc0 + bid*4 + wv;
      if (i < N){
        double v = A[(size_t)i*N + c0 + lc];
        const double* hA = hR + 32;
        const double* hB = hR + 32 + 2048;
        #pragma unroll 8
        for (int j = 0; j < 32; j++){
          double a = __shfl(v, 2*j,   64);
          double b = __shfl(v, 2*j+1, 64);
          if (lc >= 2*j+2) v += b*hA[j*64+lc] - a*hB[j*64+lc];
        }
        A[(size_t)i*N + c0 + lc] = v;
      }
    }
    gbar(grp_cnt, gcnt, ++ep);

    // trail: rank-64 Schur on lower 64x64 tiles + embedded next-diag factor
    {
      const int m = N - tc0;
      const int nt = (m + 63) >> 6;
      const int items = nt*(nt+1)/2;
      double* sPiA = shU;
      double* sPiB = shU + 1056;
      double* sPjA = shU + 2112;
      double* sPjB = shU + 3168;
      const int ty = tid >> 4, tx = tid & 15;
      int i0 = tc0, j0 = tc0, iend = tc0, jend = tc0;
      double acc[4][4];
      if (bid < items){
        {
          int I = 0, item = bid;
          while ((I+1)*(I+2)/2 <= item) I++;
          const int J = item - I*(I+1)/2;
          i0 = tc0 + I*64; j0 = tc0 + J*64;
        }
        iend = (i0 + 64 < N) ? (i0 + 64) : N;
        jend = (j0 + 64 < N) ? (j0 + 64) : N;
        if (tid < 32) sInvL[tid] = hR[tid];
        #pragma unroll
        for (int rr = 0; rr < 4; rr++)
          #pragma unroll
          for (int cc = 0; cc < 4; cc++){
            const int i = i0 + ty + 16*rr, j = j0 + tx + 16*cc;
            acc[rr][cc] = (i < iend && j < jend && i > j) ? A[(size_t)i*N + j] : 0.0;
          }
        __syncthreads();
        #pragma unroll
        for (int lh = 0; lh < 2; lh++){
          #pragma unroll
          for (int u2 = 0; u2 < 4; u2++){
            const int idx = tid + u2*256;
            const int r = idx >> 4, ll = idx & 15;
            const int l = lh*16 + ll;
            const double it = sInvL[l];
            const int gi = i0 + r;
            double a = 0.0, b = 0.0;
            if (gi < iend){
              a = A[(size_t)gi*N + c0 + 2*l];
              b = A[(size_t)gi*N + c0 + 2*l + 1];
            }
            sPiA[ll*66+r] = a; sPiB[ll*66+r] = b;
            const int gj = j0 + r;
            double a2 = 0.0, b2 = 0.0;
            if (gj < jend){
              a2 = A[(size_t)gj*N + c0 + 2*l];
              b2 = A[(size_t)gj*N + c0 + 2*l + 1];
            }
            sPjA[ll*66+r] = a2*it; sPjB[ll*66+r] = b2*it;
          }
          __syncthreads();
          #pragma unroll 4
          for (int ll = 0; ll < 16; ll++){
            double ar[4], br[4], ac2[4], bc2[4];
            #pragma unroll
            for (int rr = 0; rr < 4; rr++){
              ar[rr] = sPiA[ll*66 + ty + 16*rr];
              br[rr] = sPiB[ll*66 + ty + 16*rr];
            }
            #pragma unroll
            for (int cc = 0; cc < 4; cc++){
              ac2[cc] = sPjA[ll*66 + tx + 16*cc];
              bc2[cc] = sPjB[ll*66 + tx + 16*cc];
            }
            #pragma unroll
            for (int rr = 0; rr < 4; rr++)
              #pragma unroll
              for (int cc = 0; cc < 4; cc++)
                acc[rr][cc] += br[rr]*ac2[cc] - ar[rr]*bc2[cc];
          }
          __syncthreads();
        }
        #pragma unroll
        for (int rr = 0; rr < 4; rr++)
          #pragma unroll
          for (int cc = 0; cc < 4; cc++){
            const int i = i0 + ty + 16*rr, j = j0 + tx + 16*cc;
            if (i < iend && j < jend && i > j) A[(size_t)i*N + j] = acc[rr][cc];
          }
      }
      if (bid == 0){
        __syncthreads();
        const int wn = iend - i0;           // 64 or tail 24
        #pragma unroll
        for (int rr = 0; rr < 4; rr++)
          #pragma unroll
          for (int cc = 0; cc < 4; cc++){
            const int i = i0 + ty + 16*rr, j = j0 + tx + 16*cc;
            if (i < iend && j < jend && i > j)
              shU[(i - i0)*65 + (j - j0)] = acc[rr][cc];
          }
        __syncthreads();
        double lv; int sg;
        factor_lds(shU, sTf, wn, hW, lv, sg);
        if (tid == 0){
          double lold = atomicAdd(lacc, lv);
          int sold = atomicAdd(nneg, sg);
          if (k == 15){
            int stot = sold + sg;
            outp[0] = (stot & 1) ? -1.0f : 1.0f;
            outp[1] = (float)(lold + lv + logJa[0]);
          }
        }
      }
      gbar(grp_cnt, gcnt, ++ep);
    }
  }
}

// ---------------------------------------------------------------------------
extern "C" void kernel_launch(void* const* d_in, const int* in_sizes, int n_in,
                              void* d_out, int out_size, void* d_ws, size_t ws_size,
                              hipStream_t stream){
  (void)in_sizes; (void)n_in; (void)out_size; (void)ws_size;
  const float* x   = (const float*)d_in[0];
  const float* Fvv = (const float*)d_in[1];
  const float* Fhh = (const float*)d_in[2];
  const float* w10 = (const float*)d_in[3];
  const float* b10 = (const float*)d_in[4];
  const float* w20 = (const float*)d_in[5];
  const float* b20 = (const float*)d_in[6];
  const float* w11 = (const float*)d_in[7];
  const float* b11 = (const float*)d_in[8];
  const float* w21 = (const float*)d_in[9];
  const float* b21 = (const float*)d_in[10];
  const float* w12 = (const float*)d_in[11];
  const float* b12 = (const float*)d_in[12];
  const float* w22 = (const float*)d_in[13];
  const float* b22 = (const float*)d_in[14];
  const float* w13 = (const float*)d_in[15];
  const float* b13 = (const float*)d_in[16];
  const float* w23 = (const float*)d_in[17];
  float* outp = (float*)d_out;

  char* ws = (char*)d_ws;
  double* lacc  = (double*)(ws + 0);
  int*    nneg  = (int*)(ws + 8);
  double* logJa = (double*)(ws + 1024);
  int*    nidx  = (int*)(ws + 1088);
  unsigned* grp_cnt = (unsigned*)(ws + 6144);   // 8 lines, 128B apart
  unsigned* gcnt    = (unsigned*)(ws + 7168);
  double* hist0 = (double*)(ws + 8192);
  double* hist1 = (double*)(ws + 41216);
  const size_t CB = 589824;  // 64*2304*4
  float* tbuf  = (float*)(ws + 74240);
  float* ybuf  = (float*)(ws + 74240 + CB);
  float* hbuf0 = (float*)(ws + 74240 + 2*CB);
  float* hbuf1 = (float*)(ws + 74240 + 3*CB);
  double* A    = (double*)(ws + 74240 + 4*CB);

  hipMemsetAsync(ws + 6144, 0, 1152, stream);   // barrier counters

  void* args[] = { &x,&Fvv,&Fhh,&w10,&b10,&w20,&b20,&w11,&b11,&w21,&b21,
                   &w12,&b12,&w22,&b22,&w13,&b13,&w23,&outp,
                   &lacc,&nneg,&logJa,&nidx,&hist0,&hist1,
                   &tbuf,&ybuf,&hbuf0,&hbuf1,&A,&grp_cnt,&gcnt };
  hipLaunchCooperativeKernel((void*)k_mega, dim3(256), dim3(256), args, 0, stream);
}

// Round 7
// 1407.275 us; speedup vs baseline: 1.4748x; 1.0055x over previous
//
#include <hip/hip_runtime.h>
#include <math.h>

// ---------------------------------------------------------------------------
// HFPS R18: re-anchor. R15/R16/R17 all failed to produce data; the common
// suspect is the register factor_tile's ~500-body triangular unroll
// (compile blow-up -> harness timeout), NOT the barrier (R14's barrier ran
// green at ~12us/sync). This round is EXACT R14 (last green: 1268us kernel)
// + ONLY the conv ci software-pipeline (runtime-bounded loop, negligible
// code growth). Register factor is parked until we re-anchor.
//
// Structure (proven R12-R14):
//   P0:    block 0 prep (nidx, tbuf, zero accumulators)
//   P1-P8: conv layers on blocks 0..191 (2 units/block);
//          buildAvv tiles on blocks 192..254; block 255 factors diag tile 0
//          during P2 (LDS right-looking factor_lds, proven R11).
//   P9:    buildAs strip
//   k=0..15: panelR ; bar ; trail+embedded-next-diag-factor ; bar.
// Barrier: R14 tree (8 grp lines RELEASE-add -> gcnt add; poll gcnt
// SYSTEM-relaxed + s_sleep(2); agent acquire fence).
//
// Workspace layout:
//   0 lacc, 8 nneg, 1024 logJ, 1088 nidx[1024]
//   6144 grp_cnt[8] (128B apart), 7168 gcnt
//   8192 hist0, 41216 hist1
//   74240 tbuf/ybuf/hbuf0/hbuf1 (4 x 64*2304 fp32), 2433536 A (1048^2 f64)
// ---------------------------------------------------------------------------

#define NPIX 2304
#define MSZ  4608
#define NOCC 1024
#define NHID 24
#define PF_N 1048
#define NGRP 8

__device__ __forceinline__ void gbar(unsigned* grp_cnt, unsigned* gcnt,
                                     unsigned ep){
  __syncthreads();
  if (threadIdx.x == 0){
    unsigned* mycnt = grp_cnt + (blockIdx.x >> 5) * 32;   // 128B-spaced lines
    unsigned old = __hip_atomic_fetch_add(mycnt, 1u, __ATOMIC_RELEASE,
                                          __HIP_MEMORY_SCOPE_AGENT);
    if (old + 1u == ep * 32u){
      __hip_atomic_fetch_add(gcnt, 1u, __ATOMIC_RELEASE,
                             __HIP_MEMORY_SCOPE_AGENT);
    }
    while (__hip_atomic_load(gcnt, __ATOMIC_RELAXED,
                             __HIP_MEMORY_SCOPE_SYSTEM) < ep * (unsigned)NGRP)
      __builtin_amdgcn_s_sleep(2);
    __builtin_amdgcn_fence(__ATOMIC_ACQUIRE, "agent");
  }
  __syncthreads();
}

__device__ __forceinline__ float gelu_f(float v){
  float v3 = v*v*v;
  return 0.5f*v*(1.0f + tanhf(0.7978845608028654f*(v + 0.044715f*v3)));
}

__device__ __forceinline__ void ld15(float* d, const float* b_,
                                     int ym, int y0, int yp, const int* c5){
  #pragma unroll
  for (int rr = 0; rr < 3; rr++){
    const int rb = (rr == 0) ? ym : ((rr == 1) ? y0 : yp);
    #pragma unroll
    for (int t = 0; t < 5; t++) d[rr*5+t] = b_[rb + c5[t]];
  }
}

// ---- one conv unit: channel c, rowgroup rg; 128 threads (ltid 0..127) ----
__device__ __forceinline__ void conv_unit(int u, int tid,
    const float* __restrict__ in, const float* __restrict__ wgt,
    const float* __restrict__ bias, const float* __restrict__ res,
    float* __restrict__ outp, float* __restrict__ pre_out,
    double* __restrict__ logJ_acc,
    int cin, int resmode, int dogelu, float scale, float pre_scale){
  const int c  = u / 6;
  const int rg = u % 6;
  const int y  = rg*8 + (tid >> 4);
  const int xg = (tid & 15)*3;
  const int ym = ((y+47)%48)*48, y0 = y*48, yp = ((y+1)%48)*48;
  int c5[5];
  #pragma unroll
  for (int t = 0; t < 5; t++){
    int xx = xg - 1 + t;
    c5[t] = (xx < 0) ? 47 : ((xx >= 48) ? xx - 48 : xx);
  }
  float s0 = 0.f, s1 = 0.f, s2 = 0.f;
  const float* wp = wgt + c*cin*9;
  float cv[15], nv[15];
  ld15(cv, in, ym, y0, yp, c5);
  for (int ci = 0; ci < cin; ci++){
    const bool more = (ci + 1 < cin);
    if (more) ld15(nv, in + (ci+1)*NPIX, ym, y0, yp, c5);
    #pragma unroll
    for (int rr = 0; rr < 3; rr++){
      float v0 = cv[rr*5+0], v1 = cv[rr*5+1], v2 = cv[rr*5+2];
      float v3 = cv[rr*5+3], v4 = cv[rr*5+4];
      float w0 = wp[3*rr], w1 = wp[3*rr+1], w2 = wp[3*rr+2];
      s0 += v0*w0 + v1*w1 + v2*w2;
      s1 += v1*w0 + v2*w1 + v3*w2;
      s2 += v2*w0 + v3*w1 + v4*w2;
    }
    if (more){
      #pragma unroll
      for (int q2 = 0; q2 < 15; q2++) cv[q2] = nv[q2];
    }
    wp += 9;
  }
  const float bv = bias ? bias[c] : 0.f;
  const int base = c*NPIX + y0 + xg;
  float sv[3] = {s0, s1, s2};
  double ls = 0.0;
  #pragma unroll
  for (int t = 0; t < 3; t++){
    float s = sv[t] + bv;
    if (dogelu) s = gelu_f(s);
    if (resmode == 1) s += res[c*NPIX + y0 + xg + t];
    else if (resmode == 2) s += res[(c>>5)*NPIX + y0 + xg + t];
    s *= scale;
    outp[base+t] = s;
    if (pre_out) pre_out[base+t] = gelu_f(s * pre_scale);
    ls += (double)s;
  }
  if (logJ_acc && c >= 48){
    for (int o = 32; o > 0; o >>= 1) ls += __shfl_down(ls, o, 64);
    if ((tid & 63) == 0) atomicAdd(logJ_acc, ls);
  }
}

// ---- one 32x32 buildAvv tile (whole 256-thread block) ----
__device__ void build_avv_tile(int item, const float* __restrict__ Fvv,
      const int* __restrict__ nidx, double* __restrict__ A,
      float* G1, float* G2, int* sNi, int* sNj){
  __syncthreads();                       // protect LDS reuse across tiles
  int I = 0;
  while ((I+1)*(I+2)/2 <= item) I++;
  const int J = item - I*(I+1)/2;
  const int i0 = I*32, j0 = J*32;
  const int tid = threadIdx.x;
  if (tid < 32) sNi[tid] = nidx[i0+tid];
  else if (tid < 64) sNj[tid-32] = nidx[j0+tid-32];
  __syncthreads();
  for (int idx = tid; idx < 32*32; idx += 256){
    const int r = idx >> 5, c = idx & 31;
    G1[r*33+c] = Fvv[(size_t)sNi[r]*MSZ + sNj[c]];
    G2[r*33+c] = Fvv[(size_t)sNj[r]*MSZ + sNi[c]];
  }
  __syncthreads();
  for (int idx = tid; idx < 32*32; idx += 256){
    const int r = idx >> 5, c = idx & 31;
    const int i = i0 + r, j = j0 + c;
    if (i > j)
      A[(size_t)i*PF_N + j] = 0.5*((double)G1[r*33+c] - (double)G2[c*33+r]);
  }
}

// ---- 2x2-pivot factorization of a diag tile in LDS (proven R11-R14) ----
__device__ __forceinline__ void factor_lds(double* D, double* sTf, int w,
      double* __restrict__ histN, double& lv_out, int& sg_out){
  const int tid = threadIdx.x;
  const int r = tid & 63, qu = tid >> 6;
  const int np = w >> 1;
  for (int j = 0; j < np; j++){
    const int r0 = 2*j, r1 = r0 + 1;
    const double t = -D[r1*65 + r0];
    const double invt = 1.0 / t;
    if (tid == 0) sTf[j] = t;
    const bool rowok = (r < w) && (r >= r0 + 2);
    if (rowok){
      const double ar = D[r*65 + r0], br = D[r*65 + r1];
      if (qu == 0){
        histN[32 + j*64 + r]        = ar * invt;
        histN[32 + 2048 + j*64 + r] = br * invt;
      }
      const int lo = r0 + 2, hi = r;
      const int per = (hi - lo + 3) >> 2;
      const int cb = lo + qu*per;
      int ce = cb + per; if (ce > hi) ce = hi;
      for (int c = cb; c < ce; c++){
        const double ac = D[c*65 + r0], bc = D[c*65 + r1];
        D[r*65 + c] += (br*ac - ar*bc) * invt;
      }
    }
    __syncthreads();
  }
  if (tid < np) histN[tid] = 1.0 / sTf[tid];
  lv_out = 0.0; sg_out = 0;
  if (tid < 64){
    double lv = 0.0; int sg = 0;
    if (tid < np){ double t = sTf[tid]; lv = log(fabs(t)); sg = (t < 0.0) ? 1 : 0; }
    for (int o = 32; o > 0; o >>= 1){
      lv += __shfl_down(lv, o, 64);
      sg += __shfl_down(sg, o, 64);
    }
    if (tid == 0){ lv_out = lv; sg_out = sg; }
  }
}

// ---------------------------------------------------------------------------
__global__ __launch_bounds__(256) void k_mega(
    const float* __restrict__ x, const float* __restrict__ Fvv,
    const float* __restrict__ Fhh,
    const float* __restrict__ w10, const float* __restrict__ b10,
    const float* __restrict__ w20, const float* __restrict__ b20,
    const float* __restrict__ w11, const float* __restrict__ b11,
    const float* __restrict__ w21, const float* __restrict__ b21,
    const float* __restrict__ w12, const float* __restrict__ b12,
    const float* __restrict__ w22, const float* __restrict__ b22,
    const float* __restrict__ w13, const float* __restrict__ b13,
    const float* __restrict__ w23,
    float* __restrict__ outp,
    double* __restrict__ lacc, int* __restrict__ nneg,
    double* __restrict__ logJa, int* __restrict__ nidx,
    double* __restrict__ hist0, double* __restrict__ hist1,
    float* __restrict__ tbuf, float* __restrict__ ybuf,
    float* __restrict__ hbuf0, float* __restrict__ hbuf1,
    double* __restrict__ A, unsigned* __restrict__ grp_cnt,
    unsigned* __restrict__ gcnt){
  const int bid = blockIdx.x, tid = threadIdx.x;
  unsigned ep = 0;                 // barrier epoch
  __shared__ double shU[4224];     // union: prep / G1G2 / D / staging
  __shared__ double sInvL[32];
  __shared__ double sTf[32];

  // ---- P0: prep (block 0): nidx, tbuf = x/sqrt(2), zero accumulators ----
  if (bid == 0){
    int* cnt = (int*)shU; int* off = cnt + 256;
    if (tid == 0){ *lacc = 0.0; *nneg = 0; *logJa = 0.0; }
    int c = 0;
    for (int k2 = 0; k2 < 18; k2++){
      int idx = tid*18 + k2;
      float v = x[idx];
      c += (v == 1.0f) ? 1 : 0;
      tbuf[idx] = v * 0.70710678118654752f;
    }
    cnt[tid] = c;
    __syncthreads();
    if (tid == 0){ int s = 0; for (int q=0;q<256;q++){ off[q]=s; s+=cnt[q]; } }
    __syncthreads();
    int o = off[tid];
    for (int k2 = 0; k2 < 18; k2++){
      int idx = tid*18+k2;
      if (x[idx] == 1.0f) nidx[o++] = idx;
    }
  }
  gbar(grp_cnt, gcnt, ++ep);

  // ---- P1..P8: conv layers (bids 0..191) || buildAvv (192..254)
  //      || factor of diag tile 0 on bid 255 during P2 ----
  const float* cin_p[8] = {tbuf,ybuf,tbuf,ybuf,tbuf,ybuf,tbuf,ybuf};
  const float* w_p[8]   = {w10,w20,w11,w21,w12,w22,w13,w23};
  const float* b_p[8]   = {b10,b20,b11,b21,b12,b22,b13,nullptr};
  const float* r_p[8]   = {nullptr,x,nullptr,hbuf0,nullptr,hbuf1,nullptr,hbuf0};
  float* o_p[8]         = {ybuf,hbuf0,ybuf,hbuf1,ybuf,hbuf0,ybuf,hbuf1};
  float* pre_p[8]       = {nullptr,tbuf,nullptr,tbuf,nullptr,tbuf,nullptr,nullptr};
  const int   cinn[8]   = {2,64,64,64,64,64,64,64};
  const int   rm[8]     = {0,2,0,1,0,1,0,1};
  const int   dg[8]     = {1,0,1,0,1,0,1,0};
  const float sc[8]     = {1.f,1.f,1.f,1.f,1.f,1.f,1.f,0.44721359549995794f};
  const float ps[8]     = {0.f,0.70710678118654752f,0.f,0.57735026918962576f,
                           0.f,0.5f,0.f,0.f};
  #pragma unroll
  for (int p = 1; p <= 8; p++){
    if (bid < 192){
      conv_unit(bid*2 + (tid>>7), tid & 127,
                cin_p[p-1], w_p[p-1], b_p[p-1], r_p[p-1], o_p[p-1], pre_p[p-1],
                (p == 8) ? logJa : nullptr,
                cinn[p-1], rm[p-1], dg[p-1], sc[p-1], ps[p-1]);
    } else if (bid < 255){
      float* G1 = (float*)shU;
      float* G2 = G1 + 32*33;
      int* sNi = (int*)(G2 + 32*33);
      int* sNj = sNi + 32;
      for (int t = (p-1)*66 + (bid-192); t < p*66; t += 63)
        build_avv_tile(t, Fvv, nidx, A, G1, G2, sNi, sNj);
    } else if (p == 2){
      // diag tile 0 factor (A-tile built in P1), hidden under conv L2
      for (int idx = tid; idx < 64*64; idx += 256){
        int r = idx >> 6, c = idx & 63;
        if (r > c) shU[r*65+c] = A[(size_t)r*PF_N + c];
      }
      __syncthreads();
      double lv; int sg;
      factor_lds(shU, sTf, 64, hist0, lv, sg);
      if (tid == 0){ atomicAdd(lacc, lv); atomicAdd(nneg, sg); }
    }
    gbar(grp_cnt, gcnt, ++ep);
  }

  // ---- P9: buildAs strip (rows 1024..1047) ----
  {
    int g0 = bid*256 + tid;
    if (g0 < 24*PF_N){
      const int i = NOCC + g0 / PF_N, j = g0 % PF_N;
      if (j < i){
        const int r = i - NOCC;
        double v;
        if (j < NOCC){
          int nj = nidx[j];
          int ss = (nj >= NPIX) ? 1 : 0;
          v = -(double)hbuf1[(2*r+ss)*NPIX + (nj - ss*NPIX)];
        } else {
          int r2 = j - NOCC;
          v = 0.5*((double)Fhh[r*NHID + r2] - (double)Fhh[r2*NHID + r]);
        }
        A[(size_t)i*PF_N + j] = v;
      }
    }
  }
  gbar(grp_cnt, gcnt, ++ep);

  // ---- Pfaffian loop: 16 x (panelR ; bar ; trail+factor ; bar) ----
  for (int k = 0; k < 16; k++){
    const double* hR = (k & 1) ? hist1 : hist0;
    double* hW = (k & 1) ? hist0 : hist1;
    const int N = PF_N, c0 = 64*k, tc0 = c0 + 64;

    // panelR: one wave per trailing row
    {
      const int wv = tid >> 6, lc = tid & 63;
      const int i = tc0 + bid*4 + wv;
      if (i < N){
        double v = A[(size_t)i*N + c0 + lc];
        const double* hA = hR + 32;
        const double* hB = hR + 32 + 2048;
        #pragma unroll 8
        for (int j = 0; j < 32; j++){
          double a = __shfl(v, 2*j,   64);
          double b = __shfl(v, 2*j+1, 64);
          if (lc >= 2*j+2) v += b*hA[j*64+lc] - a*hB[j*64+lc];
        }
        A[(size_t)i*N + c0 + lc] = v;
      }
    }
    gbar(grp_cnt, gcnt, ++ep);

    // trail: rank-64 Schur on lower 64x64 tiles + embedded next-diag factor
    {
      const int m = N - tc0;
      const int nt = (m + 63) >> 6;
      const int items = nt*(nt+1)/2;
      double* sPiA = shU;
      double* sPiB = shU + 1056;
      double* sPjA = shU + 2112;
      double* sPjB = shU + 3168;
      const int ty = tid >> 4, tx = tid & 15;
      int i0 = tc0, j0 = tc0, iend = tc0, jend = tc0;
      double acc[4][4];
      if (bid < items){
        {
          int I = 0, item = bid;
          while ((I+1)*(I+2)/2 <= item) I++;
          const int J = item - I*(I+1)/2;
          i0 = tc0 + I*64; j0 = tc0 + J*64;
        }
        iend = (i0 + 64 < N) ? (i0 + 64) : N;
        jend = (j0 + 64 < N) ? (j0 + 64) : N;
        if (tid < 32) sInvL[tid] = hR[tid];
        #pragma unroll
        for (int rr = 0; rr < 4; rr++)
          #pragma unroll
          for (int cc = 0; cc < 4; cc++){
            const int i = i0 + ty + 16*rr, j = j0 + tx + 16*cc;
            acc[rr][cc] = (i < iend && j < jend && i > j) ? A[(size_t)i*N + j] : 0.0;
          }
        __syncthreads();
        #pragma unroll
        for (int lh = 0; lh < 2; lh++){
          #pragma unroll
          for (int u2 = 0; u2 < 4; u2++){
            const int idx = tid + u2*256;
            const int r = idx >> 4, ll = idx & 15;
            const int l = lh*16 + ll;
            const double it = sInvL[l];
            const int gi = i0 + r;
            double a = 0.0, b = 0.0;
            if (gi < iend){
              a = A[(size_t)gi*N + c0 + 2*l];
              b = A[(size_t)gi*N + c0 + 2*l + 1];
            }
            sPiA[ll*66+r] = a; sPiB[ll*66+r] = b;
            const int gj = j0 + r;
            double a2 = 0.0, b2 = 0.0;
            if (gj < jend){
              a2 = A[(size_t)gj*N + c0 + 2*l];
              b2 = A[(size_t)gj*N + c0 + 2*l + 1];
            }
            sPjA[ll*66+r] = a2*it; sPjB[ll*66+r] = b2*it;
          }
          __syncthreads();
          #pragma unroll 4
          for (int ll = 0; ll < 16; ll++){
            double ar[4], br[4], ac2[4], bc2[4];
            #pragma unroll
            for (int rr = 0; rr < 4; rr++){
              ar[rr] = sPiA[ll*66 + ty + 16*rr];
              br[rr] = sPiB[ll*66 + ty + 16*rr];
            }
            #pragma unroll
            for (int cc = 0; cc < 4; cc++){
              ac2[cc] = sPjA[ll*66 + tx + 16*cc];
              bc2[cc] = sPjB[ll*66 + tx + 16*cc];
            }
            #pragma unroll
            for (int rr = 0; rr < 4; rr++)
              #pragma unroll
              for (int cc = 0; cc < 4; cc++)
                acc[rr][cc] += br[rr]*ac2[cc] - ar[rr]*bc2[cc];
          }
          __syncthreads();
        }
        #pragma unroll
        for (int rr = 0; rr < 4; rr++)
          #pragma unroll
          for (int cc = 0; cc < 4; cc++){
            const int i = i0 + ty + 16*rr, j = j0 + tx + 16*cc;
            if (i < iend && j < jend && i > j) A[(size_t)i*N + j] = acc[rr][cc];
          }
      }
      if (bid == 0){
        __syncthreads();
        const int wn = iend - i0;           // 64 or tail 24
        #pragma unroll
        for (int rr = 0; rr < 4; rr++)
          #pragma unroll
          for (int cc = 0; cc < 4; cc++){
            const int i = i0 + ty + 16*rr, j = j0 + tx + 16*cc;
            if (i < iend && j < jend && i > j)
              shU[(i - i0)*65 + (j - j0)] = acc[rr][cc];
          }
        __syncthreads();
        double lv; int sg;
        factor_lds(shU, sTf, wn, hW, lv, sg);
        if (tid == 0){
          double lold = atomicAdd(lacc, lv);
          int sold = atomicAdd(nneg, sg);
          if (k == 15){
            int stot = sold + sg;
            outp[0] = (stot & 1) ? -1.0f : 1.0f;
            outp[1] = (float)(lold + lv + logJa[0]);
          }
        }
      }
      gbar(grp_cnt, gcnt, ++ep);
    }
  }
}

// ---------------------------------------------------------------------------
extern "C" void kernel_launch(void* const* d_in, const int* in_sizes, int n_in,
                              void* d_out, int out_size, void* d_ws, size_t ws_size,
                              hipStream_t stream){
  (void)in_sizes; (void)n_in; (void)out_size; (void)ws_size;
  const float* x   = (const float*)d_in[0];
  const float* Fvv = (const float*)d_in[1];
  const float* Fhh = (const float*)d_in[2];
  const float* w10 = (const float*)d_in[3];
  const float* b10 = (const float*)d_in[4];
  const float* w20 = (const float*)d_in[5];
  const float* b20 = (const float*)d_in[6];
  const float* w11 = (const float*)d_in[7];
  const float* b11 = (const float*)d_in[8];
  const float* w21 = (const float*)d_in[9];
  const float* b21 = (const float*)d_in[10];
  const float* w12 = (const float*)d_in[11];
  const float* b12 = (const float*)d_in[12];
  const float* w22 = (const float*)d_in[13];
  const float* b22 = (const float*)d_in[14];
  const float* w13 = (const float*)d_in[15];
  const float* b13 = (const float*)d_in[16];
  const float* w23 = (const float*)d_in[17];
  float* outp = (float*)d_out;

  char* ws = (char*)d_ws;
  double* lacc  = (double*)(ws + 0);
  int*    nneg  = (int*)(ws + 8);
  double* logJa = (double*)(ws + 1024);
  int*    nidx  = (int*)(ws + 1088);
  unsigned* grp_cnt = (unsigned*)(ws + 6144);   // 8 lines, 128B apart
  unsigned* gcnt    = (unsigned*)(ws + 7168);
  double* hist0 = (double*)(ws + 8192);
  double* hist1 = (double*)(ws + 41216);
  const size_t CB = 589824;  // 64*2304*4
  float* tbuf  = (float*)(ws + 74240);
  float* ybuf  = (float*)(ws + 74240 + CB);
  float* hbuf0 = (float*)(ws + 74240 + 2*CB);
  float* hbuf1 = (float*)(ws + 74240 + 3*CB);
  double* A    = (double*)(ws + 74240 + 4*CB);

  hipMemsetAsync(ws + 6144, 0, 2048, stream);   // barrier counters

  void* args[] = { &x,&Fvv,&Fhh,&w10,&b10,&w20,&b20,&w11,&b11,&w21,&b21,
                   &w12,&b12,&w22,&b22,&w13,&b13,&w23,&outp,
                   &lacc,&nneg,&logJa,&nidx,&hist0,&hist1,
                   &tbuf,&ybuf,&hbuf0,&hbuf1,&A,&grp_cnt,&gcnt };
  hipLaunchCooperativeKernel((void*)k_mega, dim3(256), dim3(256), args, 0, stream);
}

// Round 8
// 1401.421 us; speedup vs baseline: 1.4809x; 1.0042x over previous
//
#include <hip/hip_runtime.h>
#include <math.h>

// ---------------------------------------------------------------------------
// HFPS R19: RMW-free flat grid barrier.
// R18 green (1237us kernel): failure streak was the register factor's unroll
// (compile blow-up), barrier exonerated. Budget: 42 bar x ~12us = 500us
// dominates. R14-tree barrier cost = arrival RMW serialization (32 RMW/line
// ~250ns each at LLC). This round replaces ONLY the barrier:
//   - arrival: each block release-STORES epoch to its own 8B slot (posted
//     write, no serialization).
//   - block 0: 256 threads scan the 256 slots in parallel (system-relaxed
//     load + __syncthreads_count), then acquire fence + release-store 'go'.
//   - others: poll 'go' (read-only, single writer) system-relaxed + sleep;
//     watchdog re-stores their slot every 8192 spins (heals lost stores).
// Math/phases byte-identical to R18 (absmax must stay 0).
//
// Workspace layout:
//   0 lacc, 8 nneg, 1024 logJ, 1088 nidx[1024]
//   5248 go (4B), 6144 slots[256] (8B apart, 2048B)
//   8192 hist0, 41216 hist1
//   74240 tbuf/ybuf/hbuf0/hbuf1 (4 x 64*2304 fp32), 2433536 A (1048^2 f64)
// ---------------------------------------------------------------------------

#define NPIX 2304
#define MSZ  4608
#define NOCC 1024
#define NHID 24
#define PF_N 1048

__device__ __forceinline__ void gbar(unsigned* slots, unsigned* go,
                                     unsigned ep){
  __syncthreads();
  const int bid = blockIdx.x, tid = threadIdx.x;
  if (bid == 0){
    if (tid == 0)
      __hip_atomic_store(slots, ep, __ATOMIC_RELEASE,
                         __HIP_MEMORY_SCOPE_SYSTEM);
    for (;;){
      unsigned v = __hip_atomic_load(slots + tid*2, __ATOMIC_RELAXED,
                                     __HIP_MEMORY_SCOPE_SYSTEM);
      if (__syncthreads_count((v >= ep) ? 1 : 0) == 256) break;
      __builtin_amdgcn_s_sleep(1);
    }
    if (tid == 0){
      __builtin_amdgcn_fence(__ATOMIC_ACQUIRE, "agent");
      __hip_atomic_store(go, ep, __ATOMIC_RELEASE,
                         __HIP_MEMORY_SCOPE_SYSTEM);
    }
    __syncthreads();
  } else {
    if (tid == 0){
      __hip_atomic_store(slots + bid*2, ep, __ATOMIC_RELEASE,
                         __HIP_MEMORY_SCOPE_SYSTEM);
      int spins = 0;
      while (__hip_atomic_load(go, __ATOMIC_RELAXED,
                               __HIP_MEMORY_SCOPE_SYSTEM) < ep){
        __builtin_amdgcn_s_sleep(1);
        if (++spins >= 8192){        // watchdog: refresh arrival store
          spins = 0;
          __hip_atomic_store(slots + bid*2, ep, __ATOMIC_RELEASE,
                             __HIP_MEMORY_SCOPE_SYSTEM);
        }
      }
      __builtin_amdgcn_fence(__ATOMIC_ACQUIRE, "agent");
    }
    __syncthreads();
  }
}

__device__ __forceinline__ float gelu_f(float v){
  float v3 = v*v*v;
  return 0.5f*v*(1.0f + tanhf(0.7978845608028654f*(v + 0.044715f*v3)));
}

__device__ __forceinline__ void ld15(float* d, const float* b_,
                                     int ym, int y0, int yp, const int* c5){
  #pragma unroll
  for (int rr = 0; rr < 3; rr++){
    const int rb = (rr == 0) ? ym : ((rr == 1) ? y0 : yp);
    #pragma unroll
    for (int t = 0; t < 5; t++) d[rr*5+t] = b_[rb + c5[t]];
  }
}

// ---- one conv unit: channel c, rowgroup rg; 128 threads (ltid 0..127) ----
__device__ __forceinline__ void conv_unit(int u, int tid,
    const float* __restrict__ in, const float* __restrict__ wgt,
    const float* __restrict__ bias, const float* __restrict__ res,
    float* __restrict__ outp, float* __restrict__ pre_out,
    double* __restrict__ logJ_acc,
    int cin, int resmode, int dogelu, float scale, float pre_scale){
  const int c  = u / 6;
  const int rg = u % 6;
  const int y  = rg*8 + (tid >> 4);
  const int xg = (tid & 15)*3;
  const int ym = ((y+47)%48)*48, y0 = y*48, yp = ((y+1)%48)*48;
  int c5[5];
  #pragma unroll
  for (int t = 0; t < 5; t++){
    int xx = xg - 1 + t;
    c5[t] = (xx < 0) ? 47 : ((xx >= 48) ? xx - 48 : xx);
  }
  float s0 = 0.f, s1 = 0.f, s2 = 0.f;
  const float* wp = wgt + c*cin*9;
  float cv[15], nv[15];
  ld15(cv, in, ym, y0, yp, c5);
  for (int ci = 0; ci < cin; ci++){
    const bool more = (ci + 1 < cin);
    if (more) ld15(nv, in + (ci+1)*NPIX, ym, y0, yp, c5);
    #pragma unroll
    for (int rr = 0; rr < 3; rr++){
      float v0 = cv[rr*5+0], v1 = cv[rr*5+1], v2 = cv[rr*5+2];
      float v3 = cv[rr*5+3], v4 = cv[rr*5+4];
      float w0 = wp[3*rr], w1 = wp[3*rr+1], w2 = wp[3*rr+2];
      s0 += v0*w0 + v1*w1 + v2*w2;
      s1 += v1*w0 + v2*w1 + v3*w2;
      s2 += v2*w0 + v3*w1 + v4*w2;
    }
    if (more){
      #pragma unroll
      for (int q2 = 0; q2 < 15; q2++) cv[q2] = nv[q2];
    }
    wp += 9;
  }
  const float bv = bias ? bias[c] : 0.f;
  const int base = c*NPIX + y0 + xg;
  float sv[3] = {s0, s1, s2};
  double ls = 0.0;
  #pragma unroll
  for (int t = 0; t < 3; t++){
    float s = sv[t] + bv;
    if (dogelu) s = gelu_f(s);
    if (resmode == 1) s += res[c*NPIX + y0 + xg + t];
    else if (resmode == 2) s += res[(c>>5)*NPIX + y0 + xg + t];
    s *= scale;
    outp[base+t] = s;
    if (pre_out) pre_out[base+t] = gelu_f(s * pre_scale);
    ls += (double)s;
  }
  if (logJ_acc && c >= 48){
    for (int o = 32; o > 0; o >>= 1) ls += __shfl_down(ls, o, 64);
    if ((tid & 63) == 0) atomicAdd(logJ_acc, ls);
  }
}

// ---- one 32x32 buildAvv tile (whole 256-thread block) ----
__device__ void build_avv_tile(int item, const float* __restrict__ Fvv,
      const int* __restrict__ nidx, double* __restrict__ A,
      float* G1, float* G2, int* sNi, int* sNj){
  __syncthreads();                       // protect LDS reuse across tiles
  int I = 0;
  while ((I+1)*(I+2)/2 <= item) I++;
  const int J = item - I*(I+1)/2;
  const int i0 = I*32, j0 = J*32;
  const int tid = threadIdx.x;
  if (tid < 32) sNi[tid] = nidx[i0+tid];
  else if (tid < 64) sNj[tid-32] = nidx[j0+tid-32];
  __syncthreads();
  for (int idx = tid; idx < 32*32; idx += 256){
    const int r = idx >> 5, c = idx & 31;
    G1[r*33+c] = Fvv[(size_t)sNi[r]*MSZ + sNj[c]];
    G2[r*33+c] = Fvv[(size_t)sNj[r]*MSZ + sNi[c]];
  }
  __syncthreads();
  for (int idx = tid; idx < 32*32; idx += 256){
    const int r = idx >> 5, c = idx & 31;
    const int i = i0 + r, j = j0 + c;
    if (i > j)
      A[(size_t)i*PF_N + j] = 0.5*((double)G1[r*33+c] - (double)G2[c*33+r]);
  }
}

// ---- 2x2-pivot factorization of a diag tile in LDS (proven R11-R18) ----
__device__ __forceinline__ void factor_lds(double* D, double* sTf, int w,
      double* __restrict__ histN, double& lv_out, int& sg_out){
  const int tid = threadIdx.x;
  const int r = tid & 63, qu = tid >> 6;
  const int np = w >> 1;
  for (int j = 0; j < np; j++){
    const int r0 = 2*j, r1 = r0 + 1;
    const double t = -D[r1*65 + r0];
    const double invt = 1.0 / t;
    if (tid == 0) sTf[j] = t;
    const bool rowok = (r < w) && (r >= r0 + 2);
    if (rowok){
      const double ar = D[r*65 + r0], br = D[r*65 + r1];
      if (qu == 0){
        histN[32 + j*64 + r]        = ar * invt;
        histN[32 + 2048 + j*64 + r] = br * invt;
      }
      const int lo = r0 + 2, hi = r;
      const int per = (hi - lo + 3) >> 2;
      const int cb = lo + qu*per;
      int ce = cb + per; if (ce > hi) ce = hi;
      for (int c = cb; c < ce; c++){
        const double ac = D[c*65 + r0], bc = D[c*65 + r1];
        D[r*65 + c] += (br*ac - ar*bc) * invt;
      }
    }
    __syncthreads();
  }
  if (tid < np) histN[tid] = 1.0 / sTf[tid];
  lv_out = 0.0; sg_out = 0;
  if (tid < 64){
    double lv = 0.0; int sg = 0;
    if (tid < np){ double t = sTf[tid]; lv = log(fabs(t)); sg = (t < 0.0) ? 1 : 0; }
    for (int o = 32; o > 0; o >>= 1){
      lv += __shfl_down(lv, o, 64);
      sg += __shfl_down(sg, o, 64);
    }
    if (tid == 0){ lv_out = lv; sg_out = sg; }
  }
}

// ---------------------------------------------------------------------------
__global__ __launch_bounds__(256) void k_mega(
    const float* __restrict__ x, const float* __restrict__ Fvv,
    const float* __restrict__ Fhh,
    const float* __restrict__ w10, const float* __restrict__ b10,
    const float* __restrict__ w20, const float* __restrict__ b20,
    const float* __restrict__ w11, const float* __restrict__ b11,
    const float* __restrict__ w21, const float* __restrict__ b21,
    const float* __restrict__ w12, const float* __restrict__ b12,
    const float* __restrict__ w22, const float* __restrict__ b22,
    const float* __restrict__ w13, const float* __restrict__ b13,
    const float* __restrict__ w23,
    float* __restrict__ outp,
    double* __restrict__ lacc, int* __restrict__ nneg,
    double* __restrict__ logJa, int* __restrict__ nidx,
    double* __restrict__ hist0, double* __restrict__ hist1,
    float* __restrict__ tbuf, float* __restrict__ ybuf,
    float* __restrict__ hbuf0, float* __restrict__ hbuf1,
    double* __restrict__ A, unsigned* __restrict__ slots,
    unsigned* __restrict__ go){
  const int bid = blockIdx.x, tid = threadIdx.x;
  unsigned ep = 0;                 // barrier epoch
  __shared__ double shU[4224];     // union: prep / G1G2 / D / staging
  __shared__ double sInvL[32];
  __shared__ double sTf[32];

  // ---- P0: prep (block 0): nidx, tbuf = x/sqrt(2), zero accumulators ----
  if (bid == 0){
    int* cnt = (int*)shU; int* off = cnt + 256;
    if (tid == 0){ *lacc = 0.0; *nneg = 0; *logJa = 0.0; }
    int c = 0;
    for (int k2 = 0; k2 < 18; k2++){
      int idx = tid*18 + k2;
      float v = x[idx];
      c += (v == 1.0f) ? 1 : 0;
      tbuf[idx] = v * 0.70710678118654752f;
    }
    cnt[tid] = c;
    __syncthreads();
    if (tid == 0){ int s = 0; for (int q=0;q<256;q++){ off[q]=s; s+=cnt[q]; } }
    __syncthreads();
    int o = off[tid];
    for (int k2 = 0; k2 < 18; k2++){
      int idx = tid*18+k2;
      if (x[idx] == 1.0f) nidx[o++] = idx;
    }
  }
  gbar(slots, go, ++ep);

  // ---- P1..P8: conv layers (bids 0..191) || buildAvv (192..254)
  //      || factor of diag tile 0 on bid 255 during P2 ----
  const float* cin_p[8] = {tbuf,ybuf,tbuf,ybuf,tbuf,ybuf,tbuf,ybuf};
  const float* w_p[8]   = {w10,w20,w11,w21,w12,w22,w13,w23};
  const float* b_p[8]   = {b10,b20,b11,b21,b12,b22,b13,nullptr};
  const float* r_p[8]   = {nullptr,x,nullptr,hbuf0,nullptr,hbuf1,nullptr,hbuf0};
  float* o_p[8]         = {ybuf,hbuf0,ybuf,hbuf1,ybuf,hbuf0,ybuf,hbuf1};
  float* pre_p[8]       = {nullptr,tbuf,nullptr,tbuf,nullptr,tbuf,nullptr,nullptr};
  const int   cinn[8]   = {2,64,64,64,64,64,64,64};
  const int   rm[8]     = {0,2,0,1,0,1,0,1};
  const int   dg[8]     = {1,0,1,0,1,0,1,0};
  const float sc[8]     = {1.f,1.f,1.f,1.f,1.f,1.f,1.f,0.44721359549995794f};
  const float ps[8]     = {0.f,0.70710678118654752f,0.f,0.57735026918962576f,
                           0.f,0.5f,0.f,0.f};
  #pragma unroll
  for (int p = 1; p <= 8; p++){
    if (bid < 192){
      conv_unit(bid*2 + (tid>>7), tid & 127,
                cin_p[p-1], w_p[p-1], b_p[p-1], r_p[p-1], o_p[p-1], pre_p[p-1],
                (p == 8) ? logJa : nullptr,
                cinn[p-1], rm[p-1], dg[p-1], sc[p-1], ps[p-1]);
    } else if (bid < 255){
      float* G1 = (float*)shU;
      float* G2 = G1 + 32*33;
      int* sNi = (int*)(G2 + 32*33);
      int* sNj = sNi + 32;
      for (int t = (p-1)*66 + (bid-192); t < p*66; t += 63)
        build_avv_tile(t, Fvv, nidx, A, G1, G2, sNi, sNj);
    } else if (p == 2){
      // diag tile 0 factor (A-tile built in P1), hidden under conv L2
      for (int idx = tid; idx < 64*64; idx += 256){
        int r = idx >> 6, c = idx & 63;
        if (r > c) shU[r*65+c] = A[(size_t)r*PF_N + c];
      }
      __syncthreads();
      double lv; int sg;
      factor_lds(shU, sTf, 64, hist0, lv, sg);
      if (tid == 0){ atomicAdd(lacc, lv); atomicAdd(nneg, sg); }
    }
    gbar(slots, go, ++ep);
  }

  // ---- P9: buildAs strip (rows 1024..1047) ----
  {
    int g0 = bid*256 + tid;
    if (g0 < 24*PF_N){
      const int i = NOCC + g0 / PF_N, j = g0 % PF_N;
      if (j < i){
        const int r = i - NOCC;
        double v;
        if (j < NOCC){
          int nj = nidx[j];
          int ss = (nj >= NPIX) ? 1 : 0;
          v = -(double)hbuf1[(2*r+ss)*NPIX + (nj - ss*NPIX)];
        } else {
          int r2 = j - NOCC;
          v = 0.5*((double)Fhh[r*NHID + r2] - (double)Fhh[r2*NHID + r]);
        }
        A[(size_t)i*PF_N + j] = v;
      }
    }
  }
  gbar(slots, go, ++ep);

  // ---- Pfaffian loop: 16 x (panelR ; bar ; trail+factor ; bar) ----
  for (int k = 0; k < 16; k++){
    const double* hR = (k & 1) ? hist1 : hist0;
    double* hW = (k & 1) ? hist0 : hist1;
    const int N = PF_N, c0 = 64*k, tc0 = c0 + 64;

    // panelR: one wave per trailing row
    {
      const int wv = tid >> 6, lc = tid & 63;
      const int i = tc0 + bid*4 + wv;
      if (i < N){
        double v = A[(size_t)i*N + c0 + lc];
        const double* hA = hR + 32;
        const double* hB = hR + 32 + 2048;
        #pragma unroll 8
        for (int j = 0; j < 32; j++){
          double a = __shfl(v, 2*j,   64);
          double b = __shfl(v, 2*j+1, 64);
          if (lc >= 2*j+2) v += b*hA[j*64+lc] - a*hB[j*64+lc];
        }
        A[(size_t)i*N + c0 + lc] = v;
      }
    }
    gbar(slots, go, ++ep);

    // trail: rank-64 Schur on lower 64x64 tiles + embedded next-diag factor
    {
      const int m = N - tc0;
      const int nt = (m + 63) >> 6;
      const int items = nt*(nt+1)/2;
      double* sPiA = shU;
      double* sPiB = shU + 1056;
      double* sPjA = shU + 2112;
      double* sPjB = shU + 3168;
      const int ty = tid >> 4, tx = tid & 15;
      int i0 = tc0, j0 = tc0, iend = tc0, jend = tc0;
      double acc[4][4];
      if (bid < items){
        {
          int I = 0, item = bid;
          while ((I+1)*(I+2)/2 <= item) I++;
          const int J = item - I*(I+1)/2;
          i0 = tc0 + I*64; j0 = tc0 + J*64;
        }
        iend = (i0 + 64 < N) ? (i0 + 64) : N;
        jend = (j0 + 64 < N) ? (j0 + 64) : N;
        if (tid < 32) sInvL[tid] = hR[tid];
        #pragma unroll
        for (int rr = 0; rr < 4; rr++)
          #pragma unroll
          for (int cc = 0; cc < 4; cc++){
            const int i = i0 + ty + 16*rr, j = j0 + tx + 16*cc;
            acc[rr][cc] = (i < iend && j < jend && i > j) ? A[(size_t)i*N + j] : 0.0;
          }
        __syncthreads();
        #pragma unroll
        for (int lh = 0; lh < 2; lh++){
          #pragma unroll
          for (int u2 = 0; u2 < 4; u2++){
            const int idx = tid + u2*256;
            const int r = idx >> 4, ll = idx & 15;
            const int l = lh*16 + ll;
            const double it = sInvL[l];
            const int gi = i0 + r;
            double a = 0.0, b = 0.0;
            if (gi < iend){
              a = A[(size_t)gi*N + c0 + 2*l];
              b = A[(size_t)gi*N + c0 + 2*l + 1];
            }
            sPiA[ll*66+r] = a; sPiB[ll*66+r] = b;
            const int gj = j0 + r;
            double a2 = 0.0, b2 = 0.0;
            if (gj < jend){
              a2 = A[(size_t)gj*N + c0 + 2*l];
              b2 = A[(size_t)gj*N + c0 + 2*l + 1];
            }
            sPjA[ll*66+r] = a2*it; sPjB[ll*66+r] = b2*it;
          }
          __syncthreads();
          #pragma unroll 4
          for (int ll = 0; ll < 16; ll++){
            double ar[4], br[4], ac2[4], bc2[4];
            #pragma unroll
            for (int rr = 0; rr < 4; rr++){
              ar[rr] = sPiA[ll*66 + ty + 16*rr];
              br[rr] = sPiB[ll*66 + ty + 16*rr];
            }
            #pragma unroll
            for (int cc = 0; cc < 4; cc++){
              ac2[cc] = sPjA[ll*66 + tx + 16*cc];
              bc2[cc] = sPjB[ll*66 + tx + 16*cc];
            }
            #pragma unroll
            for (int rr = 0; rr < 4; rr++)
              #pragma unroll
              for (int cc = 0; cc < 4; cc++)
                acc[rr][cc] += br[rr]*ac2[cc] - ar[rr]*bc2[cc];
          }
          __syncthreads();
        }
        #pragma unroll
        for (int rr = 0; rr < 4; rr++)
          #pragma unroll
          for (int cc = 0; cc < 4; cc++){
            const int i = i0 + ty + 16*rr, j = j0 + tx + 16*cc;
            if (i < iend && j < jend && i > j) A[(size_t)i*N + j] = acc[rr][cc];
          }
      }
      if (bid == 0){
        __syncthreads();
        const int wn = iend - i0;           // 64 or tail 24
        #pragma unroll
        for (int rr = 0; rr < 4; rr++)
          #pragma unroll
          for (int cc = 0; cc < 4; cc++){
            const int i = i0 + ty + 16*rr, j = j0 + tx + 16*cc;
            if (i < iend && j < jend && i > j)
              shU[(i - i0)*65 + (j - j0)] = acc[rr][cc];
          }
        __syncthreads();
        double lv; int sg;
        factor_lds(shU, sTf, wn, hW, lv, sg);
        if (tid == 0){
          double lold = atomicAdd(lacc, lv);
          int sold = atomicAdd(nneg, sg);
          if (k == 15){
            int stot = sold + sg;
            outp[0] = (stot & 1) ? -1.0f : 1.0f;
            outp[1] = (float)(lold + lv + logJa[0]);
          }
        }
      }
      gbar(slots, go, ++ep);
    }
  }
}

// ---------------------------------------------------------------------------
extern "C" void kernel_launch(void* const* d_in, const int* in_sizes, int n_in,
                              void* d_out, int out_size, void* d_ws, size_t ws_size,
                              hipStream_t stream){
  (void)in_sizes; (void)n_in; (void)out_size; (void)ws_size;
  const float* x   = (const float*)d_in[0];
  const float* Fvv = (const float*)d_in[1];
  const float* Fhh = (const float*)d_in[2];
  const float* w10 = (const float*)d_in[3];
  const float* b10 = (const float*)d_in[4];
  const float* w20 = (const float*)d_in[5];
  const float* b20 = (const float*)d_in[6];
  const float* w11 = (const float*)d_in[7];
  const float* b11 = (const float*)d_in[8];
  const float* w21 = (const float*)d_in[9];
  const float* b21 = (const float*)d_in[10];
  const float* w12 = (const float*)d_in[11];
  const float* b12 = (const float*)d_in[12];
  const float* w22 = (const float*)d_in[13];
  const float* b22 = (const float*)d_in[14];
  const float* w13 = (const float*)d_in[15];
  const float* b13 = (const float*)d_in[16];
  const float* w23 = (const float*)d_in[17];
  float* outp = (float*)d_out;

  char* ws = (char*)d_ws;
  double* lacc  = (double*)(ws + 0);
  int*    nneg  = (int*)(ws + 8);
  double* logJa = (double*)(ws + 1024);
  int*    nidx  = (int*)(ws + 1088);
  unsigned* go    = (unsigned*)(ws + 5248);
  unsigned* slots = (unsigned*)(ws + 6144);   // 256 slots, 8B apart
  double* hist0 = (double*)(ws + 8192);
  double* hist1 = (double*)(ws + 41216);
  const size_t CB = 589824;  // 64*2304*4
  float* tbuf  = (float*)(ws + 74240);
  float* ybuf  = (float*)(ws + 74240 + CB);
  float* hbuf0 = (float*)(ws + 74240 + 2*CB);
  float* hbuf1 = (float*)(ws + 74240 + 3*CB);
  double* A    = (double*)(ws + 74240 + 4*CB);

  hipMemsetAsync(ws + 5184, 0, 3008, stream);   // go + slots

  void* args[] = { &x,&Fvv,&Fhh,&w10,&b10,&w20,&b20,&w11,&b11,&w21,&b21,
                   &w12,&b12,&w22,&b22,&w13,&b13,&w23,&outp,
                   &lacc,&nneg,&logJa,&nidx,&hist0,&hist1,
                   &tbuf,&ybuf,&hbuf0,&hbuf1,&A,&slots,&go };
  hipLaunchCooperativeKernel((void*)k_mega, dim3(256), dim3(256), args, 0, stream);
}